// Round 6
// baseline (318.242 us; speedup 1.0000x reference)
//
#include <hip/hip_runtime.h>

// ---------------------------------------------------------------------------
// CrossMultiHeadedSelfAttention  B=2 SQ=SK=2048 D=1024 H=16 HD=64
// Round 14: kv-split attention (2x TLP). Other kernels identical to r13.
//  - 512-thread blocks, 8 waves: waves 0-3 = kv tiles 0..15, waves 4-7 =
//    kv tiles 16..31, same 128 q-rows. Inner loop identical to r13 (proven),
//    16 tiles per half, own K(2-buf)/V(3-buf) LDS per half: 80 KB total
//    -> 2 blocks/CU -> 4 waves/SIMD (was 2). VALU-latency-bound loop gains TLP.
//  - Combine: half-1 writes partial O + row-sum to LDS (stride-257, conflict-
//    free), half-0 adds + writes ctx. Reassociation is ulp-level only.
// ---------------------------------------------------------------------------

typedef unsigned short u16;
typedef __bf16 bf16x8 __attribute__((ext_vector_type(8)));
typedef float f32x4 __attribute__((ext_vector_type(4)));
typedef float f32x16 __attribute__((ext_vector_type(16)));
typedef unsigned u32x2 __attribute__((ext_vector_type(2)));

#define B_ 2
#define SQ_ 2048
#define SK_ 2048
#define D_ 1024
#define H_ 16
#define HD_ 64

__device__ __forceinline__ u16 f2bf(float f) {
  union { float f; unsigned u; } c; c.f = f;
  unsigned u = c.u;
  return (u16)((u + 0x7fffu + ((u >> 16) & 1u)) >> 16);  // RNE
}
__device__ __forceinline__ float bf2f(u16 h) {
  union { unsigned u; float f; } c; c.u = ((unsigned)h) << 16;
  return c.f;
}
__device__ __forceinline__ unsigned pack_bf16(float lo, float hi) {
  union { __bf16 h[2]; unsigned u; } c;
  c.h[0] = (__bf16)lo;
  c.h[1] = (__bf16)hi;
  return c.u;
}

#define GLOAD_LDS16(gp, lp)                                                  \
  __builtin_amdgcn_global_load_lds(                                          \
      (const __attribute__((address_space(1))) void*)(gp),                   \
      (__attribute__((address_space(3))) void*)(lp), 16, 0, 0)

// ------------------------------ fused prep ---------------------------------
__global__ __launch_bounds__(256) void prep_fused(const float* __restrict__ x,
                                                  const float* __restrict__ enc,
                                                  const float* __restrict__ Wq,
                                                  const float* __restrict__ Wk,
                                                  const float* __restrict__ Wv,
                                                  const float* __restrict__ Wo,
                                                  u16* __restrict__ xb,
                                                  u16* __restrict__ eb,
                                                  u16* __restrict__ WqT,
                                                  u16* __restrict__ WoT) {
  __shared__ float tile[64][65];
  const int id = blockIdx.x;
  const int tid = threadIdx.x;

  if (id < 8192) {  // ---- casts ----
    const float* in = (id >= 4096) ? enc : x;
    u16* out = (id >= 4096) ? eb : xb;
    int i = (id & 4095) * 256 + tid;
    float4 v = ((const float4*)in)[i];
    uint2 p;
    p.x = (unsigned)f2bf(v.x) | ((unsigned)f2bf(v.y) << 16);
    p.y = (unsigned)f2bf(v.z) | ((unsigned)f2bf(v.w) << 16);
    ((uint2*)out)[i] = p;
    return;
  }

  if (id < 8960) {  // ---- Wq/Wk/Wv transpose: [h][1024][64] -> [n][1024] ----
    const int f = id - 8192;
    const int z48 = f >> 4, y = f & 15;
    const int mat = z48 >> 4, head = z48 & 15;
    const float* W = (mat == 0) ? Wq : (mat == 1 ? Wk : Wv);
    const float* ib = W + (long)head * 65536;                 // [1024][64]
    u16* ob = WqT + ((long)mat << 20) + (long)head * 65536;   // 64 x 1024
    const int r0 = y << 6;
#pragma unroll
    for (int i = 0; i < 16; ++i) {
      int idx = tid + (i << 8);
      int r = idx >> 6, c = idx & 63;
      tile[r][c] = ib[(long)(r0 + r) * 64 + c];
    }
    __syncthreads();
#pragma unroll
    for (int i = 0; i < 16; ++i) {
      int idx = tid + (i << 8);
      int cc = idx >> 6, rr = idx & 63;
      ob[(long)cc * 1024 + (r0 + rr)] = f2bf(tile[rr][cc]);
    }
    return;
  }

  {  // ---- Wo transpose 1024x1024 -> WoT [1024][1024] ----
    const int g = id - 8960;
    const int c0 = (g & 15) << 6, r0 = (g >> 4) << 6;
#pragma unroll
    for (int i = 0; i < 16; ++i) {
      int idx = tid + (i << 8);
      int r = idx >> 6, c = idx & 63;
      tile[r][c] = Wo[(long)(r0 + r) * 1024 + (c0 + c)];
    }
    __syncthreads();
#pragma unroll
    for (int i = 0; i < 16; ++i) {
      int idx = tid + (i << 8);
      int cc = idx >> 6, rr = idx & 63;
      WoT[(long)(c0 + cc) * 1024 + (r0 + rr)] = f2bf(tile[rr][cc]);
    }
  }
}

// ------------------------- fused QKV projection ----------------------------
// grid (24, 16, 2); 128x128 tile, BK=64, XOR-chunk swizzled LDS.
__global__ __launch_bounds__(256) void gemm_qkv(const u16* __restrict__ xb,
                                                const u16* __restrict__ eb,
                                                const u16* __restrict__ Wt3,
                                                const float* __restrict__ bq,
                                                const float* __restrict__ bk,
                                                const float* __restrict__ bv,
                                                u16* __restrict__ qws,
                                                u16* __restrict__ kws,
                                                u16* __restrict__ vT) {
  constexpr int M = 2048, N = 1024, K = 1024;
  __shared__ __align__(16) u16 As[128 * 64];   // 16 KB
  __shared__ __align__(16) u16 Bs[128 * 64];   // 16 KB
  const int tid = threadIdx.x;
  const int lane = tid & 63;
  const int wid = tid >> 6;
  const int l16 = lane & 15, quad = lane >> 4;
  const int wm = wid >> 1, wn = wid & 1;
  const int bn0g = blockIdx.x << 7;
  const int seg = bn0g >> 10;          // 0=Q 1=K 2=V (block-uniform)
  const int bn0 = bn0g & (N - 1);
  const int bm0 = blockIdx.y << 7;
  const u16* A = (seg == 0) ? xb : eb;
  const u16* Wt = Wt3 + ((long)seg << 20);
  const float* bias = (seg == 0) ? bq : (seg == 1 ? bk : bv);
  const long abase = (long)blockIdx.z * M * K;

  f32x4 acc[4][4];
#pragma unroll
  for (int i = 0; i < 4; ++i)
#pragma unroll
    for (int j = 0; j < 4; ++j) acc[i][j] = f32x4{0.f, 0.f, 0.f, 0.f};

  const int r0 = tid >> 3;
  const int c0s = ((tid & 7) ^ (r0 & 7)) << 3;
  const u16* agp = A + abase + (long)(bm0 + r0) * K + c0s;
  const u16* bgp = Wt + (long)(bn0 + r0) * K + c0s;
  u16* alp = As + tid * 8;
  u16* blp = Bs + tid * 8;

  for (int k0 = 0; k0 < K; k0 += 64) {
#pragma unroll
    for (int i = 0; i < 4; ++i) {
      GLOAD_LDS16(agp + k0 + (long)(32 * i) * K, alp + i * 2048);
      GLOAD_LDS16(bgp + k0 + (long)(32 * i) * K, blp + i * 2048);
    }
    __syncthreads();
#pragma unroll
    for (int kk = 0; kk < 2; ++kk) {
      const int csw = ((quad + 4 * kk) ^ (l16 & 7)) << 3;
      bf16x8 af[4], bfr[4];
#pragma unroll
      for (int mi = 0; mi < 4; ++mi)
        af[mi] = *(const bf16x8*)(As + (wm * 64 + mi * 16 + l16) * 64 + csw);
#pragma unroll
      for (int ni = 0; ni < 4; ++ni)
        bfr[ni] = *(const bf16x8*)(Bs + (wn * 64 + ni * 16 + l16) * 64 + csw);
#pragma unroll
      for (int mi = 0; mi < 4; ++mi)
#pragma unroll
        for (int ni = 0; ni < 4; ++ni)
          acc[mi][ni] = __builtin_amdgcn_mfma_f32_16x16x32_bf16(af[mi], bfr[ni],
                                                                acc[mi][ni], 0, 0, 0);
    }
    __syncthreads();
  }

  float bv4[4];
#pragma unroll
  for (int ni = 0; ni < 4; ++ni) bv4[ni] = bias[bn0 + wn * 64 + ni * 16 + l16];

  if (seg == 2) {  // transposed bf16 out [z][N][M]
    const long zb = (long)blockIdx.z * N * M;
#pragma unroll
    for (int mi = 0; mi < 4; ++mi)
#pragma unroll
      for (int ni = 0; ni < 4; ++ni) {
        int colg = bn0 + wn * 64 + ni * 16 + l16;
        int rowg = bm0 + wm * 64 + mi * 16 + (quad << 2);
        ushort4 pk = make_ushort4(f2bf(acc[mi][ni][0] + bv4[ni]),
                                  f2bf(acc[mi][ni][1] + bv4[ni]),
                                  f2bf(acc[mi][ni][2] + bv4[ni]),
                                  f2bf(acc[mi][ni][3] + bv4[ni]));
        *(ushort4*)(vT + zb + (long)colg * M + rowg) = pk;
      }
  } else {
    u16* outp = seg ? kws : qws;
    const long cbase = (long)blockIdx.z * M * N;
#pragma unroll
    for (int mi = 0; mi < 4; ++mi)
#pragma unroll
      for (int ni = 0; ni < 4; ++ni)
#pragma unroll
        for (int r = 0; r < 4; ++r) {
          int row = bm0 + wm * 64 + mi * 16 + (quad << 2) + r;
          int col = bn0 + wn * 64 + ni * 16 + l16;
          outp[cbase + (long)row * N + col] = f2bf(acc[mi][ni][r] + bv4[ni]);
        }
  }
}

// ------------------------- final GEMM (64x128 tile, BK=64) -----------------
__global__ __launch_bounds__(256) void gemm_final(const u16* __restrict__ A,
                                                  const u16* __restrict__ Wt,
                                                  const float* __restrict__ bias,
                                                  float* __restrict__ C) {
  constexpr int M = 2048, N = 1024, K = 1024;
  __shared__ __align__(16) u16 As[64 * 64];    // 8 KB
  __shared__ __align__(16) u16 Bs[128 * 64];   // 16 KB
  const int tid = threadIdx.x;
  const int lane = tid & 63;
  const int wid = tid >> 6;
  const int l16 = lane & 15, quad = lane >> 4;
  const int bn0 = blockIdx.x << 7, bm0 = blockIdx.y << 6;

  f32x4 acc[4][2];
#pragma unroll
  for (int i = 0; i < 4; ++i)
#pragma unroll
    for (int j = 0; j < 2; ++j) acc[i][j] = f32x4{0.f, 0.f, 0.f, 0.f};

  const int r0 = tid >> 3;
  const int c0s = ((tid & 7) ^ (r0 & 7)) << 3;
  const long abase = (long)blockIdx.z * M * K;
  const u16* agp = A + abase + (long)(bm0 + r0) * K + c0s;
  const u16* bgp = Wt + (long)(bn0 + r0) * K + c0s;
  u16* alp = As + tid * 8;
  u16* blp = Bs + tid * 8;

  for (int k0 = 0; k0 < K; k0 += 64) {
#pragma unroll
    for (int i = 0; i < 2; ++i)
      GLOAD_LDS16(agp + k0 + (long)(32 * i) * K, alp + i * 2048);
#pragma unroll
    for (int i = 0; i < 4; ++i)
      GLOAD_LDS16(bgp + k0 + (long)(32 * i) * K, blp + i * 2048);
    __syncthreads();
#pragma unroll
    for (int kk = 0; kk < 2; ++kk) {
      const int csw = ((quad + 4 * kk) ^ (l16 & 7)) << 3;
      bf16x8 af[4], bfr[2];
#pragma unroll
      for (int mi = 0; mi < 4; ++mi)
        af[mi] = *(const bf16x8*)(As + (mi * 16 + l16) * 64 + csw);
#pragma unroll
      for (int ni = 0; ni < 2; ++ni)
        bfr[ni] = *(const bf16x8*)(Bs + (wid * 32 + ni * 16 + l16) * 64 + csw);
#pragma unroll
      for (int mi = 0; mi < 4; ++mi)
#pragma unroll
        for (int ni = 0; ni < 2; ++ni)
          acc[mi][ni] = __builtin_amdgcn_mfma_f32_16x16x32_bf16(af[mi], bfr[ni],
                                                                acc[mi][ni], 0, 0, 0);
    }
    __syncthreads();
  }

  float bv2[2];
#pragma unroll
  for (int ni = 0; ni < 2; ++ni) bv2[ni] = bias[bn0 + wid * 32 + ni * 16 + l16];
  const long cbase = (long)blockIdx.z * M * N;
#pragma unroll
  for (int mi = 0; mi < 4; ++mi)
#pragma unroll
    for (int ni = 0; ni < 2; ++ni)
#pragma unroll
      for (int r = 0; r < 4; ++r) {
        int row = bm0 + mi * 16 + (quad << 2) + r;
        int col = bn0 + wid * 32 + ni * 16 + l16;
        C[cbase + (long)row * N + col] = acc[mi][ni][r] + bv2[ni];
      }
}

// --------------------------- flash attention (r14) -------------------------
// 512 thr / 8 waves; waves 0-3 kv-half 0, waves 4-7 kv-half 1.
// Per half: r13 inner loop over 16 tiles, own K(2-buf) + V(3-buf) LDS.
#define ATTN_STAGE(kbase, vbase)                                              \
  do {                                                                        \
    GLOAD_LDS16(kp, (kbase) + st * 8);                                        \
    GLOAD_LDS16(kp + (long)32 * D_, (kbase) + 2048 + st * 8);                 \
    GLOAD_LDS16(vp, (vbase) + st * 8);                                        \
    GLOAD_LDS16(vp + (long)32 * SK_, (vbase) + 2048 + st * 8);                \
    kp += (long)64 * D_;                                                      \
    vp += 64;                                                                 \
  } while (0)

#define QK_BLOCK(Kb, sx0, sx1)                                                \
  do {                                                                        \
    {                                                                         \
      bf16x8 kf0 = *(const bf16x8*)((Kb) + ro0 + sw[0]);                      \
      bf16x8 kf1 = *(const bf16x8*)((Kb) + 2048 + ro0 + sw[0]);               \
      sx0 = __builtin_amdgcn_mfma_f32_32x32x16_bf16(kf0, qf[0], ZV, 0, 0, 0); \
      sx1 = __builtin_amdgcn_mfma_f32_32x32x16_bf16(kf1, qf[0], ZV, 0, 0, 0); \
    }                                                                         \
    _Pragma("unroll") for (int j = 1; j < 4; ++j) {                           \
      bf16x8 kf0 = *(const bf16x8*)((Kb) + ro0 + sw[j]);                      \
      bf16x8 kf1 = *(const bf16x8*)((Kb) + 2048 + ro0 + sw[j]);               \
      sx0 = __builtin_amdgcn_mfma_f32_32x32x16_bf16(kf0, qf[j], sx0, 0, 0, 0);\
      sx1 = __builtin_amdgcn_mfma_f32_32x32x16_bf16(kf1, qf[j], sx1, 0, 0, 0);\
    }                                                                         \
  } while (0)

#define EXPD(sx0, sx1)                                                        \
  do {                                                                        \
    _Pragma("unroll") for (int g = 0; g < 8; ++g) {                           \
      float a0 = __expf(sx0[2 * g]);                                          \
      float a1 = __expf(sx0[2 * g + 1]);                                      \
      float b0 = __expf(sx1[2 * g]);                                          \
      float b1 = __expf(sx1[2 * g + 1]);                                      \
      psA += a0 + a1;                                                         \
      psB += b0 + b1;                                                         \
      d0[g] = pack_bf16(a0, a1);                                              \
      d1[g] = pack_bf16(b0, b1);                                              \
    }                                                                         \
  } while (0)

#define PV_KS(Vb, dd, k1, ks)                                                 \
  do {                                                                        \
    u32x2 sA = __builtin_amdgcn_permlane32_swap(dd[4 * (k1)],                 \
                                                dd[4 * (k1) + 2], false,      \
                                                false);                       \
    u32x2 sB = __builtin_amdgcn_permlane32_swap(dd[4 * (k1) + 1],             \
                                                dd[4 * (k1) + 3], false,      \
                                                false);                       \
    union { unsigned u[4]; bf16x8 v; } pa;                                    \
    pa.u[0] = sA[0]; pa.u[1] = sB[0]; pa.u[2] = sA[1]; pa.u[3] = sB[1];       \
    bf16x8 v0 = *(const bf16x8*)((Vb) + ro0 + sw[ks]);                        \
    bf16x8 v1 = *(const bf16x8*)((Vb) + 2048 + ro0 + sw[ks]);                 \
    o0 = __builtin_amdgcn_mfma_f32_32x32x16_bf16(pa.v, v0, o0, 0, 0, 0);      \
    o1 = __builtin_amdgcn_mfma_f32_32x32x16_bf16(pa.v, v1, o1, 0, 0, 0);      \
  } while (0)

#define PV4(Vb)                                                               \
  do {                                                                        \
    PV_KS(Vb, d0, 0, 0);                                                      \
    PV_KS(Vb, d0, 1, 1);                                                      \
    PV_KS(Vb, d1, 0, 2);                                                      \
    PV_KS(Vb, d1, 1, 3);                                                      \
  } while (0)

__global__ __launch_bounds__(512, 4) void attn_flash(const u16* __restrict__ q,
                                                     const u16* __restrict__ k,
                                                     const u16* __restrict__ vT,
                                                     u16* __restrict__ ctx) {
  // carve: Ks half0 [0,8192) half1 [8192,16384); Vs half0 [16384,28672)
  //        half1 [28672,40960)  (u16 units; 80 KB total)
  __shared__ __align__(16) u16 SM[40960];

  const int tid = threadIdx.x;
  const int lane = tid & 63;
  const int wid = tid >> 6;
  const int half = wid >> 2;        // kv half
  const int wq = wid & 3;
  const int l31 = lane & 31, h5 = lane >> 5;
  const int h = blockIdx.y, b = blockIdx.z;
  const int q0w = (blockIdx.x << 7) + (wq << 5);

  u16* Ksh = SM + half * 8192;
  u16* Vsh = SM + 16384 + half * 12288;

  // Q fragments, pre-scaled by 0.125 (exact in bf16); both halves same Q rows
  bf16x8 qf[4];
  const u16* qp = q + ((long)(b * SQ_ + q0w + l31) * D_ + h * HD_ + 8 * h5);
#pragma unroll
  for (int j = 0; j < 4; ++j) {
    bf16x8 t = *(const bf16x8*)(qp + 16 * j);
#pragma unroll
    for (int e = 0; e < 8; ++e) t[e] = (__bf16)((float)t[e] * 0.125f);
    qf[j] = t;
  }

  // staging: per-half 256 threads, 8 lanes/row, source pre-swizzled
  const int st = tid & 255;
  const int srow = st >> 3;
  const int ssw = ((st & 7) ^ (srow & 7)) << 3;
  const u16* kp = k + ((long)(b * SK_ + (half << 10) + srow) * D_ + h * HD_ + ssw);
  const u16* vp = vT + ((long)(b * D_ + h * HD_ + srow) * SK_ + (half << 10) + ssw);

  const int ro0 = l31 << 6;
  int sw[4];
#pragma unroll
  for (int i = 0; i < 4; ++i) sw[i] = ((2 * i + h5) ^ (lane & 7)) << 3;

  f32x16 o0, o1, sA0, sA1, sB0, sB1;
  f32x16 ZV = {};
#pragma unroll
  for (int i = 0; i < 16; ++i) { o0[i] = 0.f; o1[i] = 0.f; }
  float psA = 0.f, psB = 0.f;
  unsigned d0[8], d1[8];

  ATTN_STAGE(Ksh, Vsh);                   // half-tile 0 -> K0, V0
  ATTN_STAGE(Ksh + 4096, Vsh + 4096);     // half-tile 1 -> K1, V1
  __syncthreads();
  QK_BLOCK(Ksh, sA0, sA1);

  int viP = 0;  // V buffer being PV'd
  int viS = 2;  // V buffer being staged

  for (int tp = 0; tp < 14; tp += 2) {
    __syncthreads();
    ATTN_STAGE(Ksh, Vsh + viS * 4096);
    viS = (viS == 2) ? 0 : viS + 1;
    QK_BLOCK(Ksh + 4096, sB0, sB1);
    EXPD(sA0, sA1);
    PV4(Vsh + viP * 4096);
    viP = (viP == 2) ? 0 : viP + 1;

    __syncthreads();
    ATTN_STAGE(Ksh + 4096, Vsh + viS * 4096);
    viS = (viS == 2) ? 0 : viS + 1;
    QK_BLOCK(Ksh, sA0, sA1);
    EXPD(sB0, sB1);
    PV4(Vsh + viP * 4096);
    viP = (viP == 2) ? 0 : viP + 1;
  }
  // tail: tiles 14, 15 of this half
  __syncthreads();
  QK_BLOCK(Ksh + 4096, sB0, sB1);
  EXPD(sA0, sA1);
  PV4(Vsh + viP * 4096);
  viP = (viP == 2) ? 0 : viP + 1;
  EXPD(sB0, sB1);
  PV4(Vsh + viP * 4096);

  // per-half row-sum (both h5 lanes end with the half's full sum for q=l31)
  float ps = psA + psB;
  ps += __shfl_xor(ps, 32, 64);

  // ---- cross-half combine via LDS (stride 257 words: conflict-free) ----
  __syncthreads();
  float* cb = (float*)SM;
  const int wl = (wq << 6) | lane;
  if (half) {
#pragma unroll
    for (int r = 0; r < 16; ++r) {
      cb[r * 257 + wl] = o0[r];
      cb[(r + 16) * 257 + wl] = o1[r];
    }
    cb[8300 + wl] = ps;
  }
  __syncthreads();
  if (!half) {
#pragma unroll
    for (int r = 0; r < 16; ++r) {
      o0[r] += cb[r * 257 + wl];
      o1[r] += cb[(r + 16) * 257 + wl];
    }
    ps += cb[8300 + wl];
    float inv = 1.f / ps;
#pragma unroll
    for (int r = 0; r < 16; ++r) {
      const int crow = (r & 3) + 8 * (r >> 2) + 4 * h5;
      float dq = __shfl(inv, crow, 64);
      long base = (long)(b * SQ_ + q0w + crow) * D_ + h * HD_ + l31;
      ctx[base] = f2bf(o0[r] * dq);
      ctx[base + 32] = f2bf(o1[r] * dq);
    }
  }
}

// ---------------------------------------------------------------------------
extern "C" void kernel_launch(void* const* d_in, const int* in_sizes, int n_in,
                              void* d_out, int out_size, void* d_ws, size_t ws_size,
                              hipStream_t stream) {
  const float* x   = (const float*)d_in[0];
  const float* enc = (const float*)d_in[1];
  const float* Wq  = (const float*)d_in[2];
  const float* bq  = (const float*)d_in[3];
  const float* Wk  = (const float*)d_in[4];
  const float* bk  = (const float*)d_in[5];
  const float* Wv  = (const float*)d_in[6];
  const float* bv  = (const float*)d_in[7];
  const float* Wo  = (const float*)d_in[8];
  const float* bo  = (const float*)d_in[9];

  const long NE_X = (long)B_ * SQ_ * D_;  // 4,194,304
  const long NE_W = (long)D_ * D_;        // 1,048,576

  // d_out (16 MiB) scratch: outA = vTp, outB = eb.
  u16* outA = (u16*)d_out;
  u16* outB = outA + NE_X;
  u16* eb  = outB;
  u16* vTp = outA;

  // d_ws (32 MiB): weights + qws/kws + (xb -> later ctx) region.
  u16* ws  = (u16*)d_ws;
  u16* WqT = ws;                    // [3][1024][1024] stacked (Wq,Wk,Wv)
  u16* WoT = WqT + 3 * NE_W;
  u16* qws = WoT + NE_W;
  u16* kws = qws + NE_X;
  u16* xb  = kws + NE_X;            // lifetime: prep -> QKV
  u16* ctx = xb;                    // lifetime: attn -> final (disjoint)

  // 1. fused prep: casts + all weight packs (9216 blocks)
  prep_fused<<<dim3(9216, 1, 1), 256, 0, stream>>>(x, enc, Wq, Wk, Wv, Wo,
                                                   xb, eb, WqT, WoT);

  // 2. fused QKV projection (768 blocks = 3/CU)
  gemm_qkv<<<dim3(24, 16, 2), 256, 0, stream>>>(xb, eb, WqT, bq, bk, bv,
                                                qws, kws, vTp);

  // 3. attention (kv-split, 512 thr, 2 blocks/CU)
  attn_flash<<<dim3(SQ_ / 128, H_, B_), 512, 0, stream>>>(qws, kws, vTp, ctx);

  // 4. output projection (fp32, overwrites all of d_out; scratch dead)
  gemm_final<<<dim3(8, 32, 2), 256, 0, stream>>>(ctx, WoT, bo, (float*)d_out);
}

// Round 7
// 210.312 us; speedup vs baseline: 1.5132x; 1.5132x over previous
//
#include <hip/hip_runtime.h>

// ---------------------------------------------------------------------------
// CrossMultiHeadedSelfAttention  B=2 SQ=SK=2048 D=1024 H=16 HD=64
// Round 15: kv-split attention, spill-free retry (others identical to r13/r14).
//  - r14's spill: __launch_bounds__(512,4) capped VGPRs at 64 -> scratch
//    (WRITE_SIZE 242 MB). Fix: __launch_bounds__(512) only.
//  - Per-wave state cut: serial per-tile loop inside each half (QK->exp->PV,
//    single sA state). TLP (4 waves/SIMD) replaces the dropped sB ILP.
//  - K 2-buf + V 2-buf per half: LDS 64 KB -> 2 blocks/CU = 16 waves/CU.
//  - Combine epilogue identical to r14 (correctness-proven).
// ---------------------------------------------------------------------------

typedef unsigned short u16;
typedef __bf16 bf16x8 __attribute__((ext_vector_type(8)));
typedef float f32x4 __attribute__((ext_vector_type(4)));
typedef float f32x16 __attribute__((ext_vector_type(16)));
typedef unsigned u32x2 __attribute__((ext_vector_type(2)));

#define B_ 2
#define SQ_ 2048
#define SK_ 2048
#define D_ 1024
#define H_ 16
#define HD_ 64

__device__ __forceinline__ u16 f2bf(float f) {
  union { float f; unsigned u; } c; c.f = f;
  unsigned u = c.u;
  return (u16)((u + 0x7fffu + ((u >> 16) & 1u)) >> 16);  // RNE
}
__device__ __forceinline__ float bf2f(u16 h) {
  union { unsigned u; float f; } c; c.u = ((unsigned)h) << 16;
  return c.f;
}
__device__ __forceinline__ unsigned pack_bf16(float lo, float hi) {
  union { __bf16 h[2]; unsigned u; } c;
  c.h[0] = (__bf16)lo;
  c.h[1] = (__bf16)hi;
  return c.u;
}

#define GLOAD_LDS16(gp, lp)                                                  \
  __builtin_amdgcn_global_load_lds(                                          \
      (const __attribute__((address_space(1))) void*)(gp),                   \
      (__attribute__((address_space(3))) void*)(lp), 16, 0, 0)

// ------------------------------ fused prep ---------------------------------
__global__ __launch_bounds__(256) void prep_fused(const float* __restrict__ x,
                                                  const float* __restrict__ enc,
                                                  const float* __restrict__ Wq,
                                                  const float* __restrict__ Wk,
                                                  const float* __restrict__ Wv,
                                                  const float* __restrict__ Wo,
                                                  u16* __restrict__ xb,
                                                  u16* __restrict__ eb,
                                                  u16* __restrict__ WqT,
                                                  u16* __restrict__ WoT) {
  __shared__ float tile[64][65];
  const int id = blockIdx.x;
  const int tid = threadIdx.x;

  if (id < 8192) {  // ---- casts ----
    const float* in = (id >= 4096) ? enc : x;
    u16* out = (id >= 4096) ? eb : xb;
    int i = (id & 4095) * 256 + tid;
    float4 v = ((const float4*)in)[i];
    uint2 p;
    p.x = (unsigned)f2bf(v.x) | ((unsigned)f2bf(v.y) << 16);
    p.y = (unsigned)f2bf(v.z) | ((unsigned)f2bf(v.w) << 16);
    ((uint2*)out)[i] = p;
    return;
  }

  if (id < 8960) {  // ---- Wq/Wk/Wv transpose: [h][1024][64] -> [n][1024] ----
    const int f = id - 8192;
    const int z48 = f >> 4, y = f & 15;
    const int mat = z48 >> 4, head = z48 & 15;
    const float* W = (mat == 0) ? Wq : (mat == 1 ? Wk : Wv);
    const float* ib = W + (long)head * 65536;                 // [1024][64]
    u16* ob = WqT + ((long)mat << 20) + (long)head * 65536;   // 64 x 1024
    const int r0 = y << 6;
#pragma unroll
    for (int i = 0; i < 16; ++i) {
      int idx = tid + (i << 8);
      int r = idx >> 6, c = idx & 63;
      tile[r][c] = ib[(long)(r0 + r) * 64 + c];
    }
    __syncthreads();
#pragma unroll
    for (int i = 0; i < 16; ++i) {
      int idx = tid + (i << 8);
      int cc = idx >> 6, rr = idx & 63;
      ob[(long)cc * 1024 + (r0 + rr)] = f2bf(tile[rr][cc]);
    }
    return;
  }

  {  // ---- Wo transpose 1024x1024 -> WoT [1024][1024] ----
    const int g = id - 8960;
    const int c0 = (g & 15) << 6, r0 = (g >> 4) << 6;
#pragma unroll
    for (int i = 0; i < 16; ++i) {
      int idx = tid + (i << 8);
      int r = idx >> 6, c = idx & 63;
      tile[r][c] = Wo[(long)(r0 + r) * 1024 + (c0 + c)];
    }
    __syncthreads();
#pragma unroll
    for (int i = 0; i < 16; ++i) {
      int idx = tid + (i << 8);
      int cc = idx >> 6, rr = idx & 63;
      WoT[(long)(c0 + cc) * 1024 + (r0 + rr)] = f2bf(tile[rr][cc]);
    }
  }
}

// ------------------------- fused QKV projection ----------------------------
// grid (24, 16, 2); 128x128 tile, BK=64, XOR-chunk swizzled LDS.
__global__ __launch_bounds__(256) void gemm_qkv(const u16* __restrict__ xb,
                                                const u16* __restrict__ eb,
                                                const u16* __restrict__ Wt3,
                                                const float* __restrict__ bq,
                                                const float* __restrict__ bk,
                                                const float* __restrict__ bv,
                                                u16* __restrict__ qws,
                                                u16* __restrict__ kws,
                                                u16* __restrict__ vT) {
  constexpr int M = 2048, N = 1024, K = 1024;
  __shared__ __align__(16) u16 As[128 * 64];   // 16 KB
  __shared__ __align__(16) u16 Bs[128 * 64];   // 16 KB
  const int tid = threadIdx.x;
  const int lane = tid & 63;
  const int wid = tid >> 6;
  const int l16 = lane & 15, quad = lane >> 4;
  const int wm = wid >> 1, wn = wid & 1;
  const int bn0g = blockIdx.x << 7;
  const int seg = bn0g >> 10;          // 0=Q 1=K 2=V (block-uniform)
  const int bn0 = bn0g & (N - 1);
  const int bm0 = blockIdx.y << 7;
  const u16* A = (seg == 0) ? xb : eb;
  const u16* Wt = Wt3 + ((long)seg << 20);
  const float* bias = (seg == 0) ? bq : (seg == 1 ? bk : bv);
  const long abase = (long)blockIdx.z * M * K;

  f32x4 acc[4][4];
#pragma unroll
  for (int i = 0; i < 4; ++i)
#pragma unroll
    for (int j = 0; j < 4; ++j) acc[i][j] = f32x4{0.f, 0.f, 0.f, 0.f};

  const int r0 = tid >> 3;
  const int c0s = ((tid & 7) ^ (r0 & 7)) << 3;
  const u16* agp = A + abase + (long)(bm0 + r0) * K + c0s;
  const u16* bgp = Wt + (long)(bn0 + r0) * K + c0s;
  u16* alp = As + tid * 8;
  u16* blp = Bs + tid * 8;

  for (int k0 = 0; k0 < K; k0 += 64) {
#pragma unroll
    for (int i = 0; i < 4; ++i) {
      GLOAD_LDS16(agp + k0 + (long)(32 * i) * K, alp + i * 2048);
      GLOAD_LDS16(bgp + k0 + (long)(32 * i) * K, blp + i * 2048);
    }
    __syncthreads();
#pragma unroll
    for (int kk = 0; kk < 2; ++kk) {
      const int csw = ((quad + 4 * kk) ^ (l16 & 7)) << 3;
      bf16x8 af[4], bfr[4];
#pragma unroll
      for (int mi = 0; mi < 4; ++mi)
        af[mi] = *(const bf16x8*)(As + (wm * 64 + mi * 16 + l16) * 64 + csw);
#pragma unroll
      for (int ni = 0; ni < 4; ++ni)
        bfr[ni] = *(const bf16x8*)(Bs + (wn * 64 + ni * 16 + l16) * 64 + csw);
#pragma unroll
      for (int mi = 0; mi < 4; ++mi)
#pragma unroll
        for (int ni = 0; ni < 4; ++ni)
          acc[mi][ni] = __builtin_amdgcn_mfma_f32_16x16x32_bf16(af[mi], bfr[ni],
                                                                acc[mi][ni], 0, 0, 0);
    }
    __syncthreads();
  }

  float bv4[4];
#pragma unroll
  for (int ni = 0; ni < 4; ++ni) bv4[ni] = bias[bn0 + wn * 64 + ni * 16 + l16];

  if (seg == 2) {  // transposed bf16 out [z][N][M]
    const long zb = (long)blockIdx.z * N * M;
#pragma unroll
    for (int mi = 0; mi < 4; ++mi)
#pragma unroll
      for (int ni = 0; ni < 4; ++ni) {
        int colg = bn0 + wn * 64 + ni * 16 + l16;
        int rowg = bm0 + wm * 64 + mi * 16 + (quad << 2);
        ushort4 pk = make_ushort4(f2bf(acc[mi][ni][0] + bv4[ni]),
                                  f2bf(acc[mi][ni][1] + bv4[ni]),
                                  f2bf(acc[mi][ni][2] + bv4[ni]),
                                  f2bf(acc[mi][ni][3] + bv4[ni]));
        *(ushort4*)(vT + zb + (long)colg * M + rowg) = pk;
      }
  } else {
    u16* outp = seg ? kws : qws;
    const long cbase = (long)blockIdx.z * M * N;
#pragma unroll
    for (int mi = 0; mi < 4; ++mi)
#pragma unroll
      for (int ni = 0; ni < 4; ++ni)
#pragma unroll
        for (int r = 0; r < 4; ++r) {
          int row = bm0 + wm * 64 + mi * 16 + (quad << 2) + r;
          int col = bn0 + wn * 64 + ni * 16 + l16;
          outp[cbase + (long)row * N + col] = f2bf(acc[mi][ni][r] + bv4[ni]);
        }
  }
}

// ------------------------- final GEMM (64x128 tile, BK=64) -----------------
__global__ __launch_bounds__(256) void gemm_final(const u16* __restrict__ A,
                                                  const u16* __restrict__ Wt,
                                                  const float* __restrict__ bias,
                                                  float* __restrict__ C) {
  constexpr int M = 2048, N = 1024, K = 1024;
  __shared__ __align__(16) u16 As[64 * 64];    // 8 KB
  __shared__ __align__(16) u16 Bs[128 * 64];   // 16 KB
  const int tid = threadIdx.x;
  const int lane = tid & 63;
  const int wid = tid >> 6;
  const int l16 = lane & 15, quad = lane >> 4;
  const int bn0 = blockIdx.x << 7, bm0 = blockIdx.y << 6;

  f32x4 acc[4][2];
#pragma unroll
  for (int i = 0; i < 4; ++i)
#pragma unroll
    for (int j = 0; j < 2; ++j) acc[i][j] = f32x4{0.f, 0.f, 0.f, 0.f};

  const int r0 = tid >> 3;
  const int c0s = ((tid & 7) ^ (r0 & 7)) << 3;
  const long abase = (long)blockIdx.z * M * K;
  const u16* agp = A + abase + (long)(bm0 + r0) * K + c0s;
  const u16* bgp = Wt + (long)(bn0 + r0) * K + c0s;
  u16* alp = As + tid * 8;
  u16* blp = Bs + tid * 8;

  for (int k0 = 0; k0 < K; k0 += 64) {
#pragma unroll
    for (int i = 0; i < 2; ++i)
      GLOAD_LDS16(agp + k0 + (long)(32 * i) * K, alp + i * 2048);
#pragma unroll
    for (int i = 0; i < 4; ++i)
      GLOAD_LDS16(bgp + k0 + (long)(32 * i) * K, blp + i * 2048);
    __syncthreads();
#pragma unroll
    for (int kk = 0; kk < 2; ++kk) {
      const int csw = ((quad + 4 * kk) ^ (l16 & 7)) << 3;
      bf16x8 af[4], bfr[2];
#pragma unroll
      for (int mi = 0; mi < 4; ++mi)
        af[mi] = *(const bf16x8*)(As + (mi * 16 + l16) * 64 + csw);
#pragma unroll
      for (int ni = 0; ni < 2; ++ni)
        bfr[ni] = *(const bf16x8*)(Bs + (wid * 32 + ni * 16 + l16) * 64 + csw);
#pragma unroll
      for (int mi = 0; mi < 4; ++mi)
#pragma unroll
        for (int ni = 0; ni < 2; ++ni)
          acc[mi][ni] = __builtin_amdgcn_mfma_f32_16x16x32_bf16(af[mi], bfr[ni],
                                                                acc[mi][ni], 0, 0, 0);
    }
    __syncthreads();
  }

  float bv2[2];
#pragma unroll
  for (int ni = 0; ni < 2; ++ni) bv2[ni] = bias[bn0 + wid * 32 + ni * 16 + l16];
  const long cbase = (long)blockIdx.z * M * N;
#pragma unroll
  for (int mi = 0; mi < 4; ++mi)
#pragma unroll
    for (int ni = 0; ni < 2; ++ni)
#pragma unroll
      for (int r = 0; r < 4; ++r) {
        int row = bm0 + mi * 16 + (quad << 2) + r;
        int col = bn0 + wid * 32 + ni * 16 + l16;
        C[cbase + (long)row * N + col] = acc[mi][ni][r] + bv2[ni];
      }
}

// --------------------------- flash attention (r15) -------------------------
// 512 thr / 8 waves; waves 0-3 kv tiles 0..15, waves 4-7 kv tiles 16..31.
// Serial per-tile loop per half (QK->exp->PV), K/V double-buffered.
// LDS 64 KB -> 2 blocks/CU = 16 waves/CU (4/SIMD).
#define ATTN_STAGE(kbase, vbase)                                              \
  do {                                                                        \
    GLOAD_LDS16(kp, (kbase) + st * 8);                                        \
    GLOAD_LDS16(kp + (long)32 * D_, (kbase) + 2048 + st * 8);                 \
    GLOAD_LDS16(vp, (vbase) + st * 8);                                        \
    GLOAD_LDS16(vp + (long)32 * SK_, (vbase) + 2048 + st * 8);                \
    kp += (long)64 * D_;                                                      \
    vp += 64;                                                                 \
  } while (0)

#define QK_BLOCK(Kb, sx0, sx1)                                                \
  do {                                                                        \
    {                                                                         \
      bf16x8 kf0 = *(const bf16x8*)((Kb) + ro0 + sw[0]);                      \
      bf16x8 kf1 = *(const bf16x8*)((Kb) + 2048 + ro0 + sw[0]);               \
      sx0 = __builtin_amdgcn_mfma_f32_32x32x16_bf16(kf0, qf[0], ZV, 0, 0, 0); \
      sx1 = __builtin_amdgcn_mfma_f32_32x32x16_bf16(kf1, qf[0], ZV, 0, 0, 0); \
    }                                                                         \
    _Pragma("unroll") for (int j = 1; j < 4; ++j) {                           \
      bf16x8 kf0 = *(const bf16x8*)((Kb) + ro0 + sw[j]);                      \
      bf16x8 kf1 = *(const bf16x8*)((Kb) + 2048 + ro0 + sw[j]);               \
      sx0 = __builtin_amdgcn_mfma_f32_32x32x16_bf16(kf0, qf[j], sx0, 0, 0, 0);\
      sx1 = __builtin_amdgcn_mfma_f32_32x32x16_bf16(kf1, qf[j], sx1, 0, 0, 0);\
    }                                                                         \
  } while (0)

#define EXPD(sx0, sx1)                                                        \
  do {                                                                        \
    _Pragma("unroll") for (int g = 0; g < 8; ++g) {                           \
      float a0 = __expf(sx0[2 * g]);                                          \
      float a1 = __expf(sx0[2 * g + 1]);                                      \
      float b0 = __expf(sx1[2 * g]);                                          \
      float b1 = __expf(sx1[2 * g + 1]);                                      \
      psA += a0 + a1;                                                         \
      psB += b0 + b1;                                                         \
      d0[g] = pack_bf16(a0, a1);                                              \
      d1[g] = pack_bf16(b0, b1);                                              \
    }                                                                         \
  } while (0)

#define PV_KS(Vb, dd, k1, ks)                                                 \
  do {                                                                        \
    u32x2 sA = __builtin_amdgcn_permlane32_swap(dd[4 * (k1)],                 \
                                                dd[4 * (k1) + 2], false,      \
                                                false);                       \
    u32x2 sB = __builtin_amdgcn_permlane32_swap(dd[4 * (k1) + 1],             \
                                                dd[4 * (k1) + 3], false,      \
                                                false);                       \
    union { unsigned u[4]; bf16x8 v; } pa;                                    \
    pa.u[0] = sA[0]; pa.u[1] = sB[0]; pa.u[2] = sA[1]; pa.u[3] = sB[1];       \
    bf16x8 v0 = *(const bf16x8*)((Vb) + ro0 + sw[ks]);                        \
    bf16x8 v1 = *(const bf16x8*)((Vb) + 2048 + ro0 + sw[ks]);                 \
    o0 = __builtin_amdgcn_mfma_f32_32x32x16_bf16(pa.v, v0, o0, 0, 0, 0);      \
    o1 = __builtin_amdgcn_mfma_f32_32x32x16_bf16(pa.v, v1, o1, 0, 0, 0);      \
  } while (0)

#define PV4(Vb)                                                               \
  do {                                                                        \
    PV_KS(Vb, d0, 0, 0);                                                      \
    PV_KS(Vb, d0, 1, 1);                                                      \
    PV_KS(Vb, d1, 0, 2);                                                      \
    PV_KS(Vb, d1, 1, 3);                                                      \
  } while (0)

__global__ __launch_bounds__(512) void attn_flash(const u16* __restrict__ q,
                                                  const u16* __restrict__ k,
                                                  const u16* __restrict__ vT,
                                                  u16* __restrict__ ctx) {
  // Ks: half0 [0,8192) half1 [8192,16384); Vs: half0 [16384,24576)
  // half1 [24576,32768)  (u16 units; 64 KB total; 2 bufs x 4096 each)
  __shared__ __align__(16) u16 SM[32768];

  const int tid = threadIdx.x;
  const int lane = tid & 63;
  const int wid = tid >> 6;
  const int half = wid >> 2;        // kv half
  const int wq = wid & 3;
  const int l31 = lane & 31, h5 = lane >> 5;
  const int h = blockIdx.y, b = blockIdx.z;
  const int q0w = (blockIdx.x << 7) + (wq << 5);

  u16* Ksh = SM + half * 8192;
  u16* Vsh = SM + 16384 + half * 8192;

  // Q fragments, pre-scaled by 0.125 (exact in bf16); both halves same Q rows
  bf16x8 qf[4];
  const u16* qp = q + ((long)(b * SQ_ + q0w + l31) * D_ + h * HD_ + 8 * h5);
#pragma unroll
  for (int j = 0; j < 4; ++j) {
    bf16x8 t = *(const bf16x8*)(qp + 16 * j);
#pragma unroll
    for (int e = 0; e < 8; ++e) t[e] = (__bf16)((float)t[e] * 0.125f);
    qf[j] = t;
  }

  // staging: per-half 256 threads, 8 lanes/row, source pre-swizzled
  const int st = tid & 255;
  const int srow = st >> 3;
  const int ssw = ((st & 7) ^ (srow & 7)) << 3;
  const u16* kp = k + ((long)(b * SK_ + (half << 10) + srow) * D_ + h * HD_ + ssw);
  const u16* vp = vT + ((long)(b * D_ + h * HD_ + srow) * SK_ + (half << 10) + ssw);

  const int ro0 = l31 << 6;
  int sw[4];
#pragma unroll
  for (int i = 0; i < 4; ++i) sw[i] = ((2 * i + h5) ^ (lane & 7)) << 3;

  f32x16 o0, o1, sA0, sA1;
  f32x16 ZV = {};
#pragma unroll
  for (int i = 0; i < 16; ++i) { o0[i] = 0.f; o1[i] = 0.f; }
  float psA = 0.f, psB = 0.f;
  unsigned d0[8], d1[8];

  ATTN_STAGE(Ksh, Vsh);  // tile 0 of this half -> buf 0

  for (int t = 0; t < 16; ++t) {
    const int cur = t & 1;
    __syncthreads();  // tile t staged; prev reads of buf cur^1 done
    if (t < 15) ATTN_STAGE(Ksh + (cur ^ 1) * 4096, Vsh + (cur ^ 1) * 4096);
    QK_BLOCK(Ksh + cur * 4096, sA0, sA1);
    EXPD(sA0, sA1);
    PV4(Vsh + cur * 4096);
  }

  // per-half row-sum (both h5 lanes end with the half's full sum for q=l31)
  float ps = psA + psB;
  ps += __shfl_xor(ps, 32, 64);

  // ---- cross-half combine via LDS (stride 257 words: conflict-free) ----
  __syncthreads();
  float* cb = (float*)SM;
  const int wl = (wq << 6) | lane;
  if (half) {
#pragma unroll
    for (int r = 0; r < 16; ++r) {
      cb[r * 257 + wl] = o0[r];
      cb[(r + 16) * 257 + wl] = o1[r];
    }
    cb[8300 + wl] = ps;
  }
  __syncthreads();
  if (!half) {
#pragma unroll
    for (int r = 0; r < 16; ++r) {
      o0[r] += cb[r * 257 + wl];
      o1[r] += cb[(r + 16) * 257 + wl];
    }
    ps += cb[8300 + wl];
    float inv = 1.f / ps;
#pragma unroll
    for (int r = 0; r < 16; ++r) {
      const int crow = (r & 3) + 8 * (r >> 2) + 4 * h5;
      float dq = __shfl(inv, crow, 64);
      long base = (long)(b * SQ_ + q0w + crow) * D_ + h * HD_ + l31;
      ctx[base] = f2bf(o0[r] * dq);
      ctx[base + 32] = f2bf(o1[r] * dq);
    }
  }
}

// ---------------------------------------------------------------------------
extern "C" void kernel_launch(void* const* d_in, const int* in_sizes, int n_in,
                              void* d_out, int out_size, void* d_ws, size_t ws_size,
                              hipStream_t stream) {
  const float* x   = (const float*)d_in[0];
  const float* enc = (const float*)d_in[1];
  const float* Wq  = (const float*)d_in[2];
  const float* bq  = (const float*)d_in[3];
  const float* Wk  = (const float*)d_in[4];
  const float* bk  = (const float*)d_in[5];
  const float* Wv  = (const float*)d_in[6];
  const float* bv  = (const float*)d_in[7];
  const float* Wo  = (const float*)d_in[8];
  const float* bo  = (const float*)d_in[9];

  const long NE_X = (long)B_ * SQ_ * D_;  // 4,194,304
  const long NE_W = (long)D_ * D_;        // 1,048,576

  // d_out (16 MiB) scratch: outA = vTp, outB = eb.
  u16* outA = (u16*)d_out;
  u16* outB = outA + NE_X;
  u16* eb  = outB;
  u16* vTp = outA;

  // d_ws (32 MiB): weights + qws/kws + (xb -> later ctx) region.
  u16* ws  = (u16*)d_ws;
  u16* WqT = ws;                    // [3][1024][1024] stacked (Wq,Wk,Wv)
  u16* WoT = WqT + 3 * NE_W;
  u16* qws = WoT + NE_W;
  u16* kws = qws + NE_X;
  u16* xb  = kws + NE_X;            // lifetime: prep -> QKV
  u16* ctx = xb;                    // lifetime: attn -> final (disjoint)

  // 1. fused prep: casts + all weight packs (9216 blocks)
  prep_fused<<<dim3(9216, 1, 1), 256, 0, stream>>>(x, enc, Wq, Wk, Wv, Wo,
                                                   xb, eb, WqT, WoT);

  // 2. fused QKV projection (768 blocks = 3/CU)
  gemm_qkv<<<dim3(24, 16, 2), 256, 0, stream>>>(xb, eb, WqT, bq, bk, bv,
                                                qws, kws, vTp);

  // 3. attention (kv-split, 512 thr, no launch-bounds min)
  attn_flash<<<dim3(SQ_ / 128, H_, B_), 512, 0, stream>>>(qws, kws, vTp, ctx);

  // 4. output projection (fp32, overwrites all of d_out; scratch dead)
  gemm_final<<<dim3(8, 32, 2), 256, 0, stream>>>(ctx, WoT, bo, (float*)d_out);
}

// Round 8
// 206.846 us; speedup vs baseline: 1.5385x; 1.0168x over previous
//
#include <hip/hip_runtime.h>

// ---------------------------------------------------------------------------
// CrossMultiHeadedSelfAttention  B=2 SQ=SK=2048 D=1024 H=16 HD=64
// Round 16: attention = kv-split (r15) + cross-tile pipeline (r12) merged.
//  - 512 thr / 8 waves; waves 0-3 kv tiles 0..15, waves 4-7 kv 16..31.
//  - Per half: stage(c+2) || QK(c+1) [MFMA] || exp(c) [VALU] -> PV(c);
//    K 2-buf + V 3-buf per half. LDS 80 KB -> 2 blocks/CU = 16 waves/CU.
//  - NO __launch_bounds__ minimum (r14 lesson: the (512,4) bound capped the
//    unified reg budget and spilled 242 MB to scratch).
//  - Combine epilogue identical to r14/r15 (correctness-proven).
// Other kernels byte-identical to r15.
// ---------------------------------------------------------------------------

typedef unsigned short u16;
typedef __bf16 bf16x8 __attribute__((ext_vector_type(8)));
typedef float f32x4 __attribute__((ext_vector_type(4)));
typedef float f32x16 __attribute__((ext_vector_type(16)));
typedef unsigned u32x2 __attribute__((ext_vector_type(2)));

#define B_ 2
#define SQ_ 2048
#define SK_ 2048
#define D_ 1024
#define H_ 16
#define HD_ 64

__device__ __forceinline__ u16 f2bf(float f) {
  union { float f; unsigned u; } c; c.f = f;
  unsigned u = c.u;
  return (u16)((u + 0x7fffu + ((u >> 16) & 1u)) >> 16);  // RNE
}
__device__ __forceinline__ float bf2f(u16 h) {
  union { unsigned u; float f; } c; c.u = ((unsigned)h) << 16;
  return c.f;
}
__device__ __forceinline__ unsigned pack_bf16(float lo, float hi) {
  union { __bf16 h[2]; unsigned u; } c;
  c.h[0] = (__bf16)lo;
  c.h[1] = (__bf16)hi;
  return c.u;
}

#define GLOAD_LDS16(gp, lp)                                                  \
  __builtin_amdgcn_global_load_lds(                                          \
      (const __attribute__((address_space(1))) void*)(gp),                   \
      (__attribute__((address_space(3))) void*)(lp), 16, 0, 0)

// ------------------------------ fused prep ---------------------------------
__global__ __launch_bounds__(256) void prep_fused(const float* __restrict__ x,
                                                  const float* __restrict__ enc,
                                                  const float* __restrict__ Wq,
                                                  const float* __restrict__ Wk,
                                                  const float* __restrict__ Wv,
                                                  const float* __restrict__ Wo,
                                                  u16* __restrict__ xb,
                                                  u16* __restrict__ eb,
                                                  u16* __restrict__ WqT,
                                                  u16* __restrict__ WoT) {
  __shared__ float tile[64][65];
  const int id = blockIdx.x;
  const int tid = threadIdx.x;

  if (id < 8192) {  // ---- casts ----
    const float* in = (id >= 4096) ? enc : x;
    u16* out = (id >= 4096) ? eb : xb;
    int i = (id & 4095) * 256 + tid;
    float4 v = ((const float4*)in)[i];
    uint2 p;
    p.x = (unsigned)f2bf(v.x) | ((unsigned)f2bf(v.y) << 16);
    p.y = (unsigned)f2bf(v.z) | ((unsigned)f2bf(v.w) << 16);
    ((uint2*)out)[i] = p;
    return;
  }

  if (id < 8960) {  // ---- Wq/Wk/Wv transpose: [h][1024][64] -> [n][1024] ----
    const int f = id - 8192;
    const int z48 = f >> 4, y = f & 15;
    const int mat = z48 >> 4, head = z48 & 15;
    const float* W = (mat == 0) ? Wq : (mat == 1 ? Wk : Wv);
    const float* ib = W + (long)head * 65536;                 // [1024][64]
    u16* ob = WqT + ((long)mat << 20) + (long)head * 65536;   // 64 x 1024
    const int r0 = y << 6;
#pragma unroll
    for (int i = 0; i < 16; ++i) {
      int idx = tid + (i << 8);
      int r = idx >> 6, c = idx & 63;
      tile[r][c] = ib[(long)(r0 + r) * 64 + c];
    }
    __syncthreads();
#pragma unroll
    for (int i = 0; i < 16; ++i) {
      int idx = tid + (i << 8);
      int cc = idx >> 6, rr = idx & 63;
      ob[(long)cc * 1024 + (r0 + rr)] = f2bf(tile[rr][cc]);
    }
    return;
  }

  {  // ---- Wo transpose 1024x1024 -> WoT [1024][1024] ----
    const int g = id - 8960;
    const int c0 = (g & 15) << 6, r0 = (g >> 4) << 6;
#pragma unroll
    for (int i = 0; i < 16; ++i) {
      int idx = tid + (i << 8);
      int r = idx >> 6, c = idx & 63;
      tile[r][c] = Wo[(long)(r0 + r) * 1024 + (c0 + c)];
    }
    __syncthreads();
#pragma unroll
    for (int i = 0; i < 16; ++i) {
      int idx = tid + (i << 8);
      int cc = idx >> 6, rr = idx & 63;
      WoT[(long)(c0 + cc) * 1024 + (r0 + rr)] = f2bf(tile[rr][cc]);
    }
  }
}

// ------------------------- fused QKV projection ----------------------------
// grid (24, 16, 2); 128x128 tile, BK=64, XOR-chunk swizzled LDS.
__global__ __launch_bounds__(256) void gemm_qkv(const u16* __restrict__ xb,
                                                const u16* __restrict__ eb,
                                                const u16* __restrict__ Wt3,
                                                const float* __restrict__ bq,
                                                const float* __restrict__ bk,
                                                const float* __restrict__ bv,
                                                u16* __restrict__ qws,
                                                u16* __restrict__ kws,
                                                u16* __restrict__ vT) {
  constexpr int M = 2048, N = 1024, K = 1024;
  __shared__ __align__(16) u16 As[128 * 64];   // 16 KB
  __shared__ __align__(16) u16 Bs[128 * 64];   // 16 KB
  const int tid = threadIdx.x;
  const int lane = tid & 63;
  const int wid = tid >> 6;
  const int l16 = lane & 15, quad = lane >> 4;
  const int wm = wid >> 1, wn = wid & 1;
  const int bn0g = blockIdx.x << 7;
  const int seg = bn0g >> 10;          // 0=Q 1=K 2=V (block-uniform)
  const int bn0 = bn0g & (N - 1);
  const int bm0 = blockIdx.y << 7;
  const u16* A = (seg == 0) ? xb : eb;
  const u16* Wt = Wt3 + ((long)seg << 20);
  const float* bias = (seg == 0) ? bq : (seg == 1 ? bk : bv);
  const long abase = (long)blockIdx.z * M * K;

  f32x4 acc[4][4];
#pragma unroll
  for (int i = 0; i < 4; ++i)
#pragma unroll
    for (int j = 0; j < 4; ++j) acc[i][j] = f32x4{0.f, 0.f, 0.f, 0.f};

  const int r0 = tid >> 3;
  const int c0s = ((tid & 7) ^ (r0 & 7)) << 3;
  const u16* agp = A + abase + (long)(bm0 + r0) * K + c0s;
  const u16* bgp = Wt + (long)(bn0 + r0) * K + c0s;
  u16* alp = As + tid * 8;
  u16* blp = Bs + tid * 8;

  for (int k0 = 0; k0 < K; k0 += 64) {
#pragma unroll
    for (int i = 0; i < 4; ++i) {
      GLOAD_LDS16(agp + k0 + (long)(32 * i) * K, alp + i * 2048);
      GLOAD_LDS16(bgp + k0 + (long)(32 * i) * K, blp + i * 2048);
    }
    __syncthreads();
#pragma unroll
    for (int kk = 0; kk < 2; ++kk) {
      const int csw = ((quad + 4 * kk) ^ (l16 & 7)) << 3;
      bf16x8 af[4], bfr[4];
#pragma unroll
      for (int mi = 0; mi < 4; ++mi)
        af[mi] = *(const bf16x8*)(As + (wm * 64 + mi * 16 + l16) * 64 + csw);
#pragma unroll
      for (int ni = 0; ni < 4; ++ni)
        bfr[ni] = *(const bf16x8*)(Bs + (wn * 64 + ni * 16 + l16) * 64 + csw);
#pragma unroll
      for (int mi = 0; mi < 4; ++mi)
#pragma unroll
        for (int ni = 0; ni < 4; ++ni)
          acc[mi][ni] = __builtin_amdgcn_mfma_f32_16x16x32_bf16(af[mi], bfr[ni],
                                                                acc[mi][ni], 0, 0, 0);
    }
    __syncthreads();
  }

  float bv4[4];
#pragma unroll
  for (int ni = 0; ni < 4; ++ni) bv4[ni] = bias[bn0 + wn * 64 + ni * 16 + l16];

  if (seg == 2) {  // transposed bf16 out [z][N][M]
    const long zb = (long)blockIdx.z * N * M;
#pragma unroll
    for (int mi = 0; mi < 4; ++mi)
#pragma unroll
      for (int ni = 0; ni < 4; ++ni) {
        int colg = bn0 + wn * 64 + ni * 16 + l16;
        int rowg = bm0 + wm * 64 + mi * 16 + (quad << 2);
        ushort4 pk = make_ushort4(f2bf(acc[mi][ni][0] + bv4[ni]),
                                  f2bf(acc[mi][ni][1] + bv4[ni]),
                                  f2bf(acc[mi][ni][2] + bv4[ni]),
                                  f2bf(acc[mi][ni][3] + bv4[ni]));
        *(ushort4*)(vT + zb + (long)colg * M + rowg) = pk;
      }
  } else {
    u16* outp = seg ? kws : qws;
    const long cbase = (long)blockIdx.z * M * N;
#pragma unroll
    for (int mi = 0; mi < 4; ++mi)
#pragma unroll
      for (int ni = 0; ni < 4; ++ni)
#pragma unroll
        for (int r = 0; r < 4; ++r) {
          int row = bm0 + wm * 64 + mi * 16 + (quad << 2) + r;
          int col = bn0 + wn * 64 + ni * 16 + l16;
          outp[cbase + (long)row * N + col] = f2bf(acc[mi][ni][r] + bv4[ni]);
        }
  }
}

// ------------------------- final GEMM (64x128 tile, BK=64) -----------------
__global__ __launch_bounds__(256) void gemm_final(const u16* __restrict__ A,
                                                  const u16* __restrict__ Wt,
                                                  const float* __restrict__ bias,
                                                  float* __restrict__ C) {
  constexpr int M = 2048, N = 1024, K = 1024;
  __shared__ __align__(16) u16 As[64 * 64];    // 8 KB
  __shared__ __align__(16) u16 Bs[128 * 64];   // 16 KB
  const int tid = threadIdx.x;
  const int lane = tid & 63;
  const int wid = tid >> 6;
  const int l16 = lane & 15, quad = lane >> 4;
  const int bn0 = blockIdx.x << 7, bm0 = blockIdx.y << 6;

  f32x4 acc[4][2];
#pragma unroll
  for (int i = 0; i < 4; ++i)
#pragma unroll
    for (int j = 0; j < 2; ++j) acc[i][j] = f32x4{0.f, 0.f, 0.f, 0.f};

  const int r0 = tid >> 3;
  const int c0s = ((tid & 7) ^ (r0 & 7)) << 3;
  const long abase = (long)blockIdx.z * M * K;
  const u16* agp = A + abase + (long)(bm0 + r0) * K + c0s;
  const u16* bgp = Wt + (long)(bn0 + r0) * K + c0s;
  u16* alp = As + tid * 8;
  u16* blp = Bs + tid * 8;

  for (int k0 = 0; k0 < K; k0 += 64) {
#pragma unroll
    for (int i = 0; i < 2; ++i)
      GLOAD_LDS16(agp + k0 + (long)(32 * i) * K, alp + i * 2048);
#pragma unroll
    for (int i = 0; i < 4; ++i)
      GLOAD_LDS16(bgp + k0 + (long)(32 * i) * K, blp + i * 2048);
    __syncthreads();
#pragma unroll
    for (int kk = 0; kk < 2; ++kk) {
      const int csw = ((quad + 4 * kk) ^ (l16 & 7)) << 3;
      bf16x8 af[4], bfr[2];
#pragma unroll
      for (int mi = 0; mi < 4; ++mi)
        af[mi] = *(const bf16x8*)(As + (mi * 16 + l16) * 64 + csw);
#pragma unroll
      for (int ni = 0; ni < 2; ++ni)
        bfr[ni] = *(const bf16x8*)(Bs + (wid * 32 + ni * 16 + l16) * 64 + csw);
#pragma unroll
      for (int mi = 0; mi < 4; ++mi)
#pragma unroll
        for (int ni = 0; ni < 2; ++ni)
          acc[mi][ni] = __builtin_amdgcn_mfma_f32_16x16x32_bf16(af[mi], bfr[ni],
                                                                acc[mi][ni], 0, 0, 0);
    }
    __syncthreads();
  }

  float bv2[2];
#pragma unroll
  for (int ni = 0; ni < 2; ++ni) bv2[ni] = bias[bn0 + wid * 32 + ni * 16 + l16];
  const long cbase = (long)blockIdx.z * M * N;
#pragma unroll
  for (int mi = 0; mi < 4; ++mi)
#pragma unroll
    for (int ni = 0; ni < 2; ++ni)
#pragma unroll
      for (int r = 0; r < 4; ++r) {
        int row = bm0 + mi * 16 + (quad << 2) + r;
        int col = bn0 + wid * 32 + ni * 16 + l16;
        C[cbase + (long)row * N + col] = acc[mi][ni][r] + bv2[ni];
      }
}

// --------------------------- flash attention (r16) -------------------------
// 512 thr / 8 waves; kv-split halves, each running the r12 pipeline over its
// 16 tiles: stage(c+2) || QK(c+1) || exp(c) -> PV(c).
// Per half: K 2-buf + V 3-buf.  LDS 80 KB -> 2 blocks/CU = 16 waves/CU.
#define ATTN_STAGE(kbase, vbase)                                              \
  do {                                                                        \
    GLOAD_LDS16(kp, (kbase) + st * 8);                                        \
    GLOAD_LDS16(kp + (long)32 * D_, (kbase) + 2048 + st * 8);                 \
    GLOAD_LDS16(vp, (vbase) + st * 8);                                        \
    GLOAD_LDS16(vp + (long)32 * SK_, (vbase) + 2048 + st * 8);                \
    kp += (long)64 * D_;                                                      \
    vp += 64;                                                                 \
  } while (0)

#define QK_BLOCK(Kb, sx0, sx1)                                                \
  do {                                                                        \
    {                                                                         \
      bf16x8 kf0 = *(const bf16x8*)((Kb) + ro0 + sw[0]);                      \
      bf16x8 kf1 = *(const bf16x8*)((Kb) + 2048 + ro0 + sw[0]);               \
      sx0 = __builtin_amdgcn_mfma_f32_32x32x16_bf16(kf0, qf[0], ZV, 0, 0, 0); \
      sx1 = __builtin_amdgcn_mfma_f32_32x32x16_bf16(kf1, qf[0], ZV, 0, 0, 0); \
    }                                                                         \
    _Pragma("unroll") for (int j = 1; j < 4; ++j) {                           \
      bf16x8 kf0 = *(const bf16x8*)((Kb) + ro0 + sw[j]);                      \
      bf16x8 kf1 = *(const bf16x8*)((Kb) + 2048 + ro0 + sw[j]);               \
      sx0 = __builtin_amdgcn_mfma_f32_32x32x16_bf16(kf0, qf[j], sx0, 0, 0, 0);\
      sx1 = __builtin_amdgcn_mfma_f32_32x32x16_bf16(kf1, qf[j], sx1, 0, 0, 0);\
    }                                                                         \
  } while (0)

#define EXPD(sx0, sx1)                                                        \
  do {                                                                        \
    _Pragma("unroll") for (int g = 0; g < 8; ++g) {                           \
      float a0 = __expf(sx0[2 * g]);                                          \
      float a1 = __expf(sx0[2 * g + 1]);                                      \
      float b0 = __expf(sx1[2 * g]);                                          \
      float b1 = __expf(sx1[2 * g + 1]);                                      \
      psA += a0 + a1;                                                         \
      psB += b0 + b1;                                                         \
      d0[g] = pack_bf16(a0, a1);                                              \
      d1[g] = pack_bf16(b0, b1);                                              \
    }                                                                         \
  } while (0)

#define PV_KS(Vb, dd, k1, ks)                                                 \
  do {                                                                        \
    u32x2 sA = __builtin_amdgcn_permlane32_swap(dd[4 * (k1)],                 \
                                                dd[4 * (k1) + 2], false,      \
                                                false);                       \
    u32x2 sB = __builtin_amdgcn_permlane32_swap(dd[4 * (k1) + 1],             \
                                                dd[4 * (k1) + 3], false,      \
                                                false);                       \
    union { unsigned u[4]; bf16x8 v; } pa;                                    \
    pa.u[0] = sA[0]; pa.u[1] = sB[0]; pa.u[2] = sA[1]; pa.u[3] = sB[1];       \
    bf16x8 v0 = *(const bf16x8*)((Vb) + ro0 + sw[ks]);                        \
    bf16x8 v1 = *(const bf16x8*)((Vb) + 2048 + ro0 + sw[ks]);                 \
    o0 = __builtin_amdgcn_mfma_f32_32x32x16_bf16(pa.v, v0, o0, 0, 0, 0);      \
    o1 = __builtin_amdgcn_mfma_f32_32x32x16_bf16(pa.v, v1, o1, 0, 0, 0);      \
  } while (0)

#define PV4(Vb)                                                               \
  do {                                                                        \
    PV_KS(Vb, d0, 0, 0);                                                      \
    PV_KS(Vb, d0, 1, 1);                                                      \
    PV_KS(Vb, d1, 0, 2);                                                      \
    PV_KS(Vb, d1, 1, 3);                                                      \
  } while (0)

__global__ __launch_bounds__(512) void attn_flash(const u16* __restrict__ q,
                                                  const u16* __restrict__ k,
                                                  const u16* __restrict__ vT,
                                                  u16* __restrict__ ctx) {
  // Ks: half0 [0,8192) half1 [8192,16384)  (2 bufs x 4096 each)
  // Vs: half0 [16384,28672) half1 [28672,40960)  (3 bufs x 4096 each)
  __shared__ __align__(16) u16 SM[40960];  // 80 KB

  const int tid = threadIdx.x;
  const int lane = tid & 63;
  const int wid = tid >> 6;
  const int half = wid >> 2;        // kv half
  const int wq = wid & 3;
  const int l31 = lane & 31, h5 = lane >> 5;
  const int h = blockIdx.y, b = blockIdx.z;
  const int q0w = (blockIdx.x << 7) + (wq << 5);

  u16* Ksh = SM + half * 8192;
  u16* Vsh = SM + 16384 + half * 12288;

  // Q fragments, pre-scaled by 0.125 (exact in bf16); both halves same Q rows
  bf16x8 qf[4];
  const u16* qp = q + ((long)(b * SQ_ + q0w + l31) * D_ + h * HD_ + 8 * h5);
#pragma unroll
  for (int j = 0; j < 4; ++j) {
    bf16x8 t = *(const bf16x8*)(qp + 16 * j);
#pragma unroll
    for (int e = 0; e < 8; ++e) t[e] = (__bf16)((float)t[e] * 0.125f);
    qf[j] = t;
  }

  // staging: per-half 256 threads, 8 lanes/row, source pre-swizzled
  const int st = tid & 255;
  const int srow = st >> 3;
  const int ssw = ((st & 7) ^ (srow & 7)) << 3;
  const u16* kp = k + ((long)(b * SK_ + (half << 10) + srow) * D_ + h * HD_ + ssw);
  const u16* vp = vT + ((long)(b * D_ + h * HD_ + srow) * SK_ + (half << 10) + ssw);

  const int ro0 = l31 << 6;
  int sw[4];
#pragma unroll
  for (int i = 0; i < 4; ++i) sw[i] = ((2 * i + h5) ^ (lane & 7)) << 3;

  f32x16 o0, o1, sA0, sA1, sB0, sB1;
  f32x16 ZV = {};
#pragma unroll
  for (int i = 0; i < 16; ++i) { o0[i] = 0.f; o1[i] = 0.f; }
  float psA = 0.f, psB = 0.f;
  unsigned d0[8], d1[8];

  // prologue: stage half-tiles 0,1; QK(0)
  ATTN_STAGE(Ksh, Vsh);                   // tile 0 -> K0, V0
  ATTN_STAGE(Ksh + 4096, Vsh + 4096);     // tile 1 -> K1, V1
  __syncthreads();
  QK_BLOCK(Ksh, sA0, sA1);

  int viP = 0;  // V buffer being PV'd   (t % 3)
  int viS = 2;  // V buffer being staged ((t+2) % 3)

  for (int tp = 0; tp < 14; tp += 2) {
    // step A (t = tp even): stage(t+2)->K0; QK(t+1) from K1
    __syncthreads();
    ATTN_STAGE(Ksh, Vsh + viS * 4096);
    viS = (viS == 2) ? 0 : viS + 1;
    QK_BLOCK(Ksh + 4096, sB0, sB1);
    EXPD(sA0, sA1);
    PV4(Vsh + viP * 4096);
    viP = (viP == 2) ? 0 : viP + 1;
    // step B (t = tp+1 odd): stage(t+2)->K1; QK(t+1) from K0
    __syncthreads();
    ATTN_STAGE(Ksh + 4096, Vsh + viS * 4096);
    viS = (viS == 2) ? 0 : viS + 1;
    QK_BLOCK(Ksh, sA0, sA1);
    EXPD(sB0, sB1);
    PV4(Vsh + viP * 4096);
    viP = (viP == 2) ? 0 : viP + 1;
  }
  // tail t=14: QK(15) from K1; finish tile 14
  __syncthreads();
  QK_BLOCK(Ksh + 4096, sB0, sB1);
  EXPD(sA0, sA1);
  PV4(Vsh + viP * 4096);
  viP = (viP == 2) ? 0 : viP + 1;
  // tail t=15: finish tile 15
  EXPD(sB0, sB1);
  PV4(Vsh + viP * 4096);

  // per-half row-sum (both h5 lanes end with the half's full sum for q=l31)
  float ps = psA + psB;
  ps += __shfl_xor(ps, 32, 64);

  // ---- cross-half combine via LDS (stride 257 words: conflict-free) ----
  __syncthreads();
  float* cb = (float*)SM;
  const int wl = (wq << 6) | lane;
  if (half) {
#pragma unroll
    for (int r = 0; r < 16; ++r) {
      cb[r * 257 + wl] = o0[r];
      cb[(r + 16) * 257 + wl] = o1[r];
    }
    cb[8300 + wl] = ps;
  }
  __syncthreads();
  if (!half) {
#pragma unroll
    for (int r = 0; r < 16; ++r) {
      o0[r] += cb[r * 257 + wl];
      o1[r] += cb[(r + 16) * 257 + wl];
    }
    ps += cb[8300 + wl];
    float inv = 1.f / ps;
#pragma unroll
    for (int r = 0; r < 16; ++r) {
      const int crow = (r & 3) + 8 * (r >> 2) + 4 * h5;
      float dq = __shfl(inv, crow, 64);
      long base = (long)(b * SQ_ + q0w + crow) * D_ + h * HD_ + l31;
      ctx[base] = f2bf(o0[r] * dq);
      ctx[base + 32] = f2bf(o1[r] * dq);
    }
  }
}

// ---------------------------------------------------------------------------
extern "C" void kernel_launch(void* const* d_in, const int* in_sizes, int n_in,
                              void* d_out, int out_size, void* d_ws, size_t ws_size,
                              hipStream_t stream) {
  const float* x   = (const float*)d_in[0];
  const float* enc = (const float*)d_in[1];
  const float* Wq  = (const float*)d_in[2];
  const float* bq  = (const float*)d_in[3];
  const float* Wk  = (const float*)d_in[4];
  const float* bk  = (const float*)d_in[5];
  const float* Wv  = (const float*)d_in[6];
  const float* bv  = (const float*)d_in[7];
  const float* Wo  = (const float*)d_in[8];
  const float* bo  = (const float*)d_in[9];

  const long NE_X = (long)B_ * SQ_ * D_;  // 4,194,304
  const long NE_W = (long)D_ * D_;        // 1,048,576

  // d_out (16 MiB) scratch: outA = vTp, outB = eb.
  u16* outA = (u16*)d_out;
  u16* outB = outA + NE_X;
  u16* eb  = outB;
  u16* vTp = outA;

  // d_ws (32 MiB): weights + qws/kws + (xb -> later ctx) region.
  u16* ws  = (u16*)d_ws;
  u16* WqT = ws;                    // [3][1024][1024] stacked (Wq,Wk,Wv)
  u16* WoT = WqT + 3 * NE_W;
  u16* qws = WoT + NE_W;
  u16* kws = qws + NE_X;
  u16* xb  = kws + NE_X;            // lifetime: prep -> QKV
  u16* ctx = xb;                    // lifetime: attn -> final (disjoint)

  // 1. fused prep: casts + all weight packs (9216 blocks)
  prep_fused<<<dim3(9216, 1, 1), 256, 0, stream>>>(x, enc, Wq, Wk, Wv, Wo,
                                                   xb, eb, WqT, WoT);

  // 2. fused QKV projection (768 blocks = 3/CU)
  gemm_qkv<<<dim3(24, 16, 2), 256, 0, stream>>>(xb, eb, WqT, bq, bk, bv,
                                                qws, kws, vTp);

  // 3. attention (kv-split + pipelined, 512 thr, 2 blocks/CU)
  attn_flash<<<dim3(SQ_ / 128, H_, B_), 512, 0, stream>>>(qws, kws, vTp, ctx);

  // 4. output projection (fp32, overwrites all of d_out; scratch dead)
  gemm_final<<<dim3(8, 32, 2), 256, 0, stream>>>(ctx, WoT, bo, (float*)d_out);
}

// Round 10
// 205.338 us; speedup vs baseline: 1.5498x; 1.0073x over previous
//
#include <hip/hip_runtime.h>

// ---------------------------------------------------------------------------
// CrossMultiHeadedSelfAttention  B=2 SQ=SK=2048 D=1024 H=16 HD=64
// Round 18: r17 with the vmcnt race FIXED.
//  - r17 bug: VMW4 at phase START followed by ds_reads with NO barrier
//    between -> wave read slices other waves hadn't confirmed -> NaN.
//  - Correct invariant (m201): vmcnt(N) -> s_barrier -> reads.
//    vmcnt(4) sits at END of P1 (confirms A1,B1 of current tile) and END of
//    P3 (confirms A0,B0 of next tile), each immediately before the closing
//    barrier. Prologue: stage 4 slices, vmcnt(4)+barrier. Tile15: vmcnt(0).
//  - lgkmcnt(0) after each pre-MFMA barrier (m201 ordering) so ds_reads
//    drain before the region's next overwrite.
//  - attn = r15 (proven), prep/gemm_final unchanged.
// ---------------------------------------------------------------------------

typedef unsigned short u16;
typedef __bf16 bf16x8 __attribute__((ext_vector_type(8)));
typedef float f32x4 __attribute__((ext_vector_type(4)));
typedef float f32x16 __attribute__((ext_vector_type(16)));
typedef unsigned u32x2 __attribute__((ext_vector_type(2)));

#define B_ 2
#define SQ_ 2048
#define SK_ 2048
#define D_ 1024
#define H_ 16
#define HD_ 64

__device__ __forceinline__ u16 f2bf(float f) {
  union { float f; unsigned u; } c; c.f = f;
  unsigned u = c.u;
  return (u16)((u + 0x7fffu + ((u >> 16) & 1u)) >> 16);  // RNE
}
__device__ __forceinline__ unsigned pack_bf16(float lo, float hi) {
  union { __bf16 h[2]; unsigned u; } c;
  c.h[0] = (__bf16)lo;
  c.h[1] = (__bf16)hi;
  return c.u;
}

#define GLOAD_LDS16(gp, lp)                                                  \
  __builtin_amdgcn_global_load_lds(                                          \
      (const __attribute__((address_space(1))) void*)(gp),                   \
      (__attribute__((address_space(3))) void*)(lp), 16, 0, 0)

// ------------------------------ fused prep ---------------------------------
__global__ __launch_bounds__(256) void prep_fused(const float* __restrict__ x,
                                                  const float* __restrict__ enc,
                                                  const float* __restrict__ Wq,
                                                  const float* __restrict__ Wk,
                                                  const float* __restrict__ Wv,
                                                  const float* __restrict__ Wo,
                                                  u16* __restrict__ xb,
                                                  u16* __restrict__ eb,
                                                  u16* __restrict__ WqT,
                                                  u16* __restrict__ WoT) {
  __shared__ float tile[64][65];
  const int id = blockIdx.x;
  const int tid = threadIdx.x;

  if (id < 8192) {  // ---- casts ----
    const float* in = (id >= 4096) ? enc : x;
    u16* out = (id >= 4096) ? eb : xb;
    int i = (id & 4095) * 256 + tid;
    float4 v = ((const float4*)in)[i];
    uint2 p;
    p.x = (unsigned)f2bf(v.x) | ((unsigned)f2bf(v.y) << 16);
    p.y = (unsigned)f2bf(v.z) | ((unsigned)f2bf(v.w) << 16);
    ((uint2*)out)[i] = p;
    return;
  }

  if (id < 8960) {  // ---- Wq/Wk/Wv transpose: [h][1024][64] -> [n][1024] ----
    const int f = id - 8192;
    const int z48 = f >> 4, y = f & 15;
    const int mat = z48 >> 4, head = z48 & 15;
    const float* W = (mat == 0) ? Wq : (mat == 1 ? Wk : Wv);
    const float* ib = W + (long)head * 65536;                 // [1024][64]
    u16* ob = WqT + ((long)mat << 20) + (long)head * 65536;   // 64 x 1024
    const int r0 = y << 6;
#pragma unroll
    for (int i = 0; i < 16; ++i) {
      int idx = tid + (i << 8);
      int r = idx >> 6, c = idx & 63;
      tile[r][c] = ib[(long)(r0 + r) * 64 + c];
    }
    __syncthreads();
#pragma unroll
    for (int i = 0; i < 16; ++i) {
      int idx = tid + (i << 8);
      int cc = idx >> 6, rr = idx & 63;
      ob[(long)cc * 1024 + (r0 + rr)] = f2bf(tile[rr][cc]);
    }
    return;
  }

  {  // ---- Wo transpose 1024x1024 -> WoT [1024][1024] ----
    const int g = id - 8960;
    const int c0 = (g & 15) << 6, r0 = (g >> 4) << 6;
#pragma unroll
    for (int i = 0; i < 16; ++i) {
      int idx = tid + (i << 8);
      int r = idx >> 6, c = idx & 63;
      tile[r][c] = Wo[(long)(r0 + r) * 1024 + (c0 + c)];
    }
    __syncthreads();
#pragma unroll
    for (int i = 0; i < 16; ++i) {
      int idx = tid + (i << 8);
      int cc = idx >> 6, rr = idx & 63;
      WoT[(long)(c0 + cc) * 1024 + (r0 + rr)] = f2bf(tile[rr][cc]);
    }
  }
}

// ------------------- fused QKV projection (8-phase 256x256) ----------------
// grid (12, 8, 2), 512 thr. seg = N'-range/1024 -> Q/K/V. BK=64, K=1024.
#define QBAR() asm volatile("s_barrier" ::: "memory")
#define VMW4 asm volatile("s_waitcnt vmcnt(4)" ::: "memory")
#define VMW0 asm volatile("s_waitcnt vmcnt(0)" ::: "memory")
#define LGKM0 asm volatile("s_waitcnt lgkmcnt(0)" ::: "memory")
#define PRIO1 __builtin_amdgcn_s_setprio(1)
#define PRIO0 __builtin_amdgcn_s_setprio(0)

// stage one [256][32] kk-slice: 2 glds (rows 0-127, 128-255)
#define ST_SLICE(gp, koff, dstu)                                              \
  do {                                                                        \
    GLOAD_LDS16((gp) + (koff), SMu + (dstu) + tid * 8);                       \
    GLOAD_LDS16((gp) + (koff) + (long)128 * 1024, SMu + (dstu) + 4096 + tid * 8); \
  } while (0)

#define LDA4(dst, bufo, kko, mho)                                             \
  _Pragma("unroll") for (int m2 = 0; m2 < 4; ++m2)                            \
      dst[m2] = *(const bf16x8*)(SMu + (bufo) + (kko) + aob + (mho) + m2 * 512)

#define LDB4(dst, bufo, kko)                                                  \
  _Pragma("unroll") for (int n2 = 0; n2 < 4; ++n2)                            \
      dst[n2] = *(const bf16x8*)(SMu + (bufo) + 16384 + (kko) + bob + n2 * 512)

#define MM16(mh, av, bv_)                                                     \
  _Pragma("unroll") for (int m2 = 0; m2 < 4; ++m2)                            \
  _Pragma("unroll") for (int n2 = 0; n2 < 4; ++n2)                            \
      acc[(mh) * 4 + m2][n2] = __builtin_amdgcn_mfma_f32_16x16x32_bf16(       \
          av[m2], bv_[n2], acc[(mh) * 4 + m2][n2], 0, 0, 0)

// 4 phases of one K-tile. Invariant at tile entry: outstanding = [A1(t),B1(t)],
// and A0(t),B0(t) confirmed (vmcnt4+barrier at end of previous tile).
#define TILE_BODY(bo, so, kn)                                                 \
  {                                                                           \
    bf16x8 aF[4], aG[4], bF[4];                                               \
    /* P0: reads A0,B0(t); stages A0(t+1) */                                  \
    LDA4(aF, bo, 0, 0); LDB4(bF, bo, 0);                                      \
    ST_SLICE(aS, (kn), (so) + 0);                                             \
    QBAR(); LGKM0; PRIO1; MM16(0, aF, bF); PRIO0; QBAR();                     \
    /* P1: reads A0-upper; stages B0(t+1); confirm A1,B1(t) */                \
    LDA4(aG, bo, 0, 2048);                                                    \
    ST_SLICE(bS, (kn), (so) + 16384);                                         \
    QBAR(); LGKM0; PRIO1; MM16(1, aG, bF); PRIO0; VMW4; QBAR();               \
    /* P2: reads A1,B1(t); stages A1(t+1) */                                  \
    LDA4(aF, bo, 8192, 0); LDB4(bF, bo, 8192);                                \
    ST_SLICE(aS, (kn) + 32, (so) + 8192);                                     \
    QBAR(); LGKM0; PRIO1; MM16(0, aF, bF); PRIO0; QBAR();                     \
    /* P3: reads A1-upper; stages B1(t+1); confirm A0,B0(t+1) */              \
    LDA4(aG, bo, 8192, 2048);                                                 \
    ST_SLICE(bS, (kn) + 32, (so) + 24576);                                    \
    QBAR(); LGKM0; PRIO1; MM16(1, aG, bF); PRIO0; VMW4; QBAR();               \
  }

__global__ __launch_bounds__(512) void gemm_qkv(const u16* __restrict__ xb,
                                                const u16* __restrict__ eb,
                                                const u16* __restrict__ Wt3,
                                                const float* __restrict__ bq,
                                                const float* __restrict__ bk,
                                                const float* __restrict__ bv,
                                                u16* __restrict__ qws,
                                                u16* __restrict__ kws,
                                                u16* __restrict__ vT) {
  constexpr int M = 2048, N = 1024, K = 1024;
  // [2 buf][A0 @0, A1 @8192, B0 @16384, B1 @24576] u16. 128 KB total.
  __shared__ __align__(16) u16 SMu[65536];

  const int tid = threadIdx.x;
  const int lane = tid & 63;
  const int wid = tid >> 6;
  const int wm = wid >> 2;          // M half (rows wm*128)
  const int wn = wid & 3;           // N quarter (cols wn*64)
  const int l16 = lane & 15, quad = lane >> 4;
  const int qsw = (quad ^ ((l16 >> 1) & 3)) << 3;   // u16 units
  const int aob = wm * 4096 + l16 * 32 + qsw;
  const int bob = wn * 2048 + l16 * 32 + qsw;

  const int bn0g = blockIdx.x << 8;
  const int seg = bn0g >> 10;       // 0=Q 1=K 2=V (block-uniform)
  const int bn0 = bn0g & (N - 1);
  const int bm0 = blockIdx.y << 8;
  const u16* A = (seg == 0) ? xb : eb;
  const u16* Wt = Wt3 + ((long)seg << 20);
  const float* bias = (seg == 0) ? bq : (seg == 1 ? bk : bv);
  const long abase = (long)blockIdx.z * M * K;

  f32x4 acc[8][4];
#pragma unroll
  for (int i = 0; i < 8; ++i)
#pragma unroll
    for (int j = 0; j < 4; ++j) acc[i][j] = f32x4{0.f, 0.f, 0.f, 0.f};

  // staging: row = tid>>2 (+128 per glds), chunk = tid&3, pre-swizzled source
  const int sr = tid >> 2;
  const int sc2 = ((tid & 3) ^ ((sr >> 1) & 3)) << 3;
  const u16* aS = A + abase + (long)(bm0 + sr) * K + sc2;
  const u16* bS = Wt + (long)(bn0 + sr) * K + sc2;

  // prologue: stage tile 0 (A0,B0,A1,B1); confirm A0,B0 before first reads
  ST_SLICE(aS, 0, 0);
  ST_SLICE(bS, 0, 16384);
  ST_SLICE(aS, 32, 8192);
  ST_SLICE(bS, 32, 24576);
  VMW4; QBAR();

  // tiles 0..13 (pairs), tile 14 stages 15, tile 15 peeled
#pragma unroll 1
  for (int tp = 0; tp < 7; ++tp) {
    const int kb = tp * 128;
    TILE_BODY(0, 32768, kb + 64);
    TILE_BODY(32768, 0, kb + 128);
  }
  TILE_BODY(0, 32768, 960);  // t=14 stages t=15
  {                          // t=15: entering outstanding = [A1(15),B1(15)]
    bf16x8 aF[4], aG[4], bF[4];
    LDA4(aF, 32768, 0, 0); LDB4(bF, 32768, 0);
    QBAR(); LGKM0; PRIO1; MM16(0, aF, bF); PRIO0; QBAR();
    LDA4(aG, 32768, 0, 2048);
    QBAR(); LGKM0; PRIO1; MM16(1, aG, bF); PRIO0; VMW0; QBAR();
    LDA4(aF, 32768, 8192, 0); LDB4(bF, 32768, 8192);
    QBAR(); LGKM0; PRIO1; MM16(0, aF, bF); PRIO0; QBAR();
    LDA4(aG, 32768, 8192, 2048);
    LGKM0; PRIO1; MM16(1, aG, bF); PRIO0;
  }

  float bv4[4];
#pragma unroll
  for (int ni = 0; ni < 4; ++ni) bv4[ni] = bias[bn0 + wn * 64 + ni * 16 + l16];

  if (seg == 2) {  // transposed bf16 out [z][N][M]
    const long zb = (long)blockIdx.z * N * M;
#pragma unroll
    for (int mi = 0; mi < 8; ++mi)
#pragma unroll
      for (int ni = 0; ni < 4; ++ni) {
        int colg = bn0 + wn * 64 + ni * 16 + l16;
        int rowg = bm0 + wm * 128 + mi * 16 + (quad << 2);
        ushort4 pk = make_ushort4(f2bf(acc[mi][ni][0] + bv4[ni]),
                                  f2bf(acc[mi][ni][1] + bv4[ni]),
                                  f2bf(acc[mi][ni][2] + bv4[ni]),
                                  f2bf(acc[mi][ni][3] + bv4[ni]));
        *(ushort4*)(vT + zb + (long)colg * M + rowg) = pk;
      }
  } else {
    u16* outp = seg ? kws : qws;
    const long cbase = (long)blockIdx.z * M * N;
#pragma unroll
    for (int mi = 0; mi < 8; ++mi)
#pragma unroll
      for (int ni = 0; ni < 4; ++ni)
#pragma unroll
        for (int r = 0; r < 4; ++r) {
          int row = bm0 + wm * 128 + mi * 16 + (quad << 2) + r;
          int col = bn0 + wn * 64 + ni * 16 + l16;
          outp[cbase + (long)row * N + col] = f2bf(acc[mi][ni][r] + bv4[ni]);
        }
  }
}

// ------------------------- final GEMM (64x128 tile, BK=64) -----------------
__global__ __launch_bounds__(256) void gemm_final(const u16* __restrict__ A,
                                                  const u16* __restrict__ Wt,
                                                  const float* __restrict__ bias,
                                                  float* __restrict__ C) {
  constexpr int M = 2048, N = 1024, K = 1024;
  __shared__ __align__(16) u16 As[64 * 64];    // 8 KB
  __shared__ __align__(16) u16 Bs[128 * 64];   // 16 KB
  const int tid = threadIdx.x;
  const int lane = tid & 63;
  const int wid = tid >> 6;
  const int l16 = lane & 15, quad = lane >> 4;
  const int bn0 = blockIdx.x << 7, bm0 = blockIdx.y << 6;

  f32x4 acc[4][2];
#pragma unroll
  for (int i = 0; i < 4; ++i)
#pragma unroll
    for (int j = 0; j < 2; ++j) acc[i][j] = f32x4{0.f, 0.f, 0.f, 0.f};

  const int r0 = tid >> 3;
  const int c0s = ((tid & 7) ^ (r0 & 7)) << 3;
  const long abase = (long)blockIdx.z * M * K;
  const u16* agp = A + abase + (long)(bm0 + r0) * K + c0s;
  const u16* bgp = Wt + (long)(bn0 + r0) * K + c0s;
  u16* alp = As + tid * 8;
  u16* blp = Bs + tid * 8;

  for (int k0 = 0; k0 < K; k0 += 64) {
#pragma unroll
    for (int i = 0; i < 2; ++i)
      GLOAD_LDS16(agp + k0 + (long)(32 * i) * K, alp + i * 2048);
#pragma unroll
    for (int i = 0; i < 4; ++i)
      GLOAD_LDS16(bgp + k0 + (long)(32 * i) * K, blp + i * 2048);
    __syncthreads();
#pragma unroll
    for (int kk = 0; kk < 2; ++kk) {
      const int csw = ((quad + 4 * kk) ^ (l16 & 7)) << 3;
      bf16x8 af[4], bfr[2];
#pragma unroll
      for (int mi = 0; mi < 4; ++mi)
        af[mi] = *(const bf16x8*)(As + (mi * 16 + l16) * 64 + csw);
#pragma unroll
      for (int ni = 0; ni < 2; ++ni)
        bfr[ni] = *(const bf16x8*)(Bs + (wid * 32 + ni * 16 + l16) * 64 + csw);
#pragma unroll
      for (int mi = 0; mi < 4; ++mi)
#pragma unroll
        for (int ni = 0; ni < 2; ++ni)
          acc[mi][ni] = __builtin_amdgcn_mfma_f32_16x16x32_bf16(af[mi], bfr[ni],
                                                                acc[mi][ni], 0, 0, 0);
    }
    __syncthreads();
  }

  float bv2[2];
#pragma unroll
  for (int ni = 0; ni < 2; ++ni) bv2[ni] = bias[bn0 + wid * 32 + ni * 16 + l16];
  const long cbase = (long)blockIdx.z * M * N;
#pragma unroll
  for (int mi = 0; mi < 4; ++mi)
#pragma unroll
    for (int ni = 0; ni < 2; ++ni)
#pragma unroll
      for (int r = 0; r < 4; ++r) {
        int row = bm0 + mi * 16 + (quad << 2) + r;
        int col = bn0 + wid * 32 + ni * 16 + l16;
        C[cbase + (long)row * N + col] = acc[mi][ni][r] + bv2[ni];
      }
}

// --------------------------- flash attention (r15, proven) -----------------
#define ATTN_STAGE(kbase, vbase)                                              \
  do {                                                                        \
    GLOAD_LDS16(kp, (kbase) + st * 8);                                        \
    GLOAD_LDS16(kp + (long)32 * D_, (kbase) + 2048 + st * 8);                 \
    GLOAD_LDS16(vp, (vbase) + st * 8);                                        \
    GLOAD_LDS16(vp + (long)32 * SK_, (vbase) + 2048 + st * 8);                \
    kp += (long)64 * D_;                                                      \
    vp += 64;                                                                 \
  } while (0)

#define QK_BLOCK(Kb, sx0, sx1)                                                \
  do {                                                                        \
    {                                                                         \
      bf16x8 kf0 = *(const bf16x8*)((Kb) + ro0 + sw[0]);                      \
      bf16x8 kf1 = *(const bf16x8*)((Kb) + 2048 + ro0 + sw[0]);               \
      sx0 = __builtin_amdgcn_mfma_f32_32x32x16_bf16(kf0, qf[0], ZV, 0, 0, 0); \
      sx1 = __builtin_amdgcn_mfma_f32_32x32x16_bf16(kf1, qf[0], ZV, 0, 0, 0); \
    }                                                                         \
    _Pragma("unroll") for (int j = 1; j < 4; ++j) {                           \
      bf16x8 kf0 = *(const bf16x8*)((Kb) + ro0 + sw[j]);                      \
      bf16x8 kf1 = *(const bf16x8*)((Kb) + 2048 + ro0 + sw[j]);               \
      sx0 = __builtin_amdgcn_mfma_f32_32x32x16_bf16(kf0, qf[j], sx0, 0, 0, 0);\
      sx1 = __builtin_amdgcn_mfma_f32_32x32x16_bf16(kf1, qf[j], sx1, 0, 0, 0);\
    }                                                                         \
  } while (0)

#define EXPD(sx0, sx1)                                                        \
  do {                                                                        \
    _Pragma("unroll") for (int g = 0; g < 8; ++g) {                           \
      float a0 = __expf(sx0[2 * g]);                                          \
      float a1 = __expf(sx0[2 * g + 1]);                                      \
      float b0 = __expf(sx1[2 * g]);                                          \
      float b1 = __expf(sx1[2 * g + 1]);                                      \
      psA += a0 + a1;                                                         \
      psB += b0 + b1;                                                         \
      d0[g] = pack_bf16(a0, a1);                                              \
      d1[g] = pack_bf16(b0, b1);                                              \
    }                                                                         \
  } while (0)

#define PV_KS(Vb, dd, k1, ks)                                                 \
  do {                                                                        \
    u32x2 sA = __builtin_amdgcn_permlane32_swap(dd[4 * (k1)],                 \
                                                dd[4 * (k1) + 2], false,      \
                                                false);                       \
    u32x2 sB = __builtin_amdgcn_permlane32_swap(dd[4 * (k1) + 1],             \
                                                dd[4 * (k1) + 3], false,      \
                                                false);                       \
    union { unsigned u[4]; bf16x8 v; } pa;                                    \
    pa.u[0] = sA[0]; pa.u[1] = sB[0]; pa.u[2] = sA[1]; pa.u[3] = sB[1];       \
    bf16x8 v0 = *(const bf16x8*)((Vb) + ro0 + sw[ks]);                        \
    bf16x8 v1 = *(const bf16x8*)((Vb) + 2048 + ro0 + sw[ks]);                 \
    o0 = __builtin_amdgcn_mfma_f32_32x32x16_bf16(pa.v, v0, o0, 0, 0, 0);      \
    o1 = __builtin_amdgcn_mfma_f32_32x32x16_bf16(pa.v, v1, o1, 0, 0, 0);      \
  } while (0)

#define PV4(Vb)                                                               \
  do {                                                                        \
    PV_KS(Vb, d0, 0, 0);                                                      \
    PV_KS(Vb, d0, 1, 1);                                                      \
    PV_KS(Vb, d1, 0, 2);                                                      \
    PV_KS(Vb, d1, 1, 3);                                                      \
  } while (0)

__global__ __launch_bounds__(512) void attn_flash(const u16* __restrict__ q,
                                                  const u16* __restrict__ k,
                                                  const u16* __restrict__ vT,
                                                  u16* __restrict__ ctx) {
  __shared__ __align__(16) u16 SM[32768];  // 64 KB

  const int tid = threadIdx.x;
  const int lane = tid & 63;
  const int wid = tid >> 6;
  const int half = wid >> 2;
  const int wq = wid & 3;
  const int l31 = lane & 31, h5 = lane >> 5;
  const int h = blockIdx.y, b = blockIdx.z;
  const int q0w = (blockIdx.x << 7) + (wq << 5);

  u16* Ksh = SM + half * 8192;
  u16* Vsh = SM + 16384 + half * 8192;

  bf16x8 qf[4];
  const u16* qp = q + ((long)(b * SQ_ + q0w + l31) * D_ + h * HD_ + 8 * h5);
#pragma unroll
  for (int j = 0; j < 4; ++j) {
    bf16x8 t = *(const bf16x8*)(qp + 16 * j);
#pragma unroll
    for (int e = 0; e < 8; ++e) t[e] = (__bf16)((float)t[e] * 0.125f);
    qf[j] = t;
  }

  const int st = tid & 255;
  const int srow = st >> 3;
  const int ssw = ((st & 7) ^ (srow & 7)) << 3;
  const u16* kp = k + ((long)(b * SK_ + (half << 10) + srow) * D_ + h * HD_ + ssw);
  const u16* vp = vT + ((long)(b * D_ + h * HD_ + srow) * SK_ + (half << 10) + ssw);

  const int ro0 = l31 << 6;
  int sw[4];
#pragma unroll
  for (int i = 0; i < 4; ++i) sw[i] = ((2 * i + h5) ^ (lane & 7)) << 3;

  f32x16 o0, o1, sA0, sA1;
  f32x16 ZV = {};
#pragma unroll
  for (int i = 0; i < 16; ++i) { o0[i] = 0.f; o1[i] = 0.f; }
  float psA = 0.f, psB = 0.f;
  unsigned d0[8], d1[8];

  ATTN_STAGE(Ksh, Vsh);  // tile 0 of this half -> buf 0

  for (int t = 0; t < 16; ++t) {
    const int cur = t & 1;
    __syncthreads();
    if (t < 15) ATTN_STAGE(Ksh + (cur ^ 1) * 4096, Vsh + (cur ^ 1) * 4096);
    QK_BLOCK(Ksh + cur * 4096, sA0, sA1);
    EXPD(sA0, sA1);
    PV4(Vsh + cur * 4096);
  }

  float ps = psA + psB;
  ps += __shfl_xor(ps, 32, 64);

  __syncthreads();
  float* cb = (float*)SM;
  const int wl = (wq << 6) | lane;
  if (half) {
#pragma unroll
    for (int r = 0; r < 16; ++r) {
      cb[r * 257 + wl] = o0[r];
      cb[(r + 16) * 257 + wl] = o1[r];
    }
    cb[8300 + wl] = ps;
  }
  __syncthreads();
  if (!half) {
#pragma unroll
    for (int r = 0; r < 16; ++r) {
      o0[r] += cb[r * 257 + wl];
      o1[r] += cb[(r + 16) * 257 + wl];
    }
    ps += cb[8300 + wl];
    float inv = 1.f / ps;
#pragma unroll
    for (int r = 0; r < 16; ++r) {
      const int crow = (r & 3) + 8 * (r >> 2) + 4 * h5;
      float dq = __shfl(inv, crow, 64);
      long base = (long)(b * SQ_ + q0w + crow) * D_ + h * HD_ + l31;
      ctx[base] = f2bf(o0[r] * dq);
      ctx[base + 32] = f2bf(o1[r] * dq);
    }
  }
}

// ---------------------------------------------------------------------------
extern "C" void kernel_launch(void* const* d_in, const int* in_sizes, int n_in,
                              void* d_out, int out_size, void* d_ws, size_t ws_size,
                              hipStream_t stream) {
  const float* x   = (const float*)d_in[0];
  const float* enc = (const float*)d_in[1];
  const float* Wq  = (const float*)d_in[2];
  const float* bq  = (const float*)d_in[3];
  const float* Wk  = (const float*)d_in[4];
  const float* bk  = (const float*)d_in[5];
  const float* Wv  = (const float*)d_in[6];
  const float* bv  = (const float*)d_in[7];
  const float* Wo  = (const float*)d_in[8];
  const float* bo  = (const float*)d_in[9];

  const long NE_X = (long)B_ * SQ_ * D_;  // 4,194,304
  const long NE_W = (long)D_ * D_;        // 1,048,576

  // d_out (16 MiB) scratch: outA = vTp, outB = eb.
  u16* outA = (u16*)d_out;
  u16* outB = outA + NE_X;
  u16* eb  = outB;
  u16* vTp = outA;

  // d_ws (32 MiB): weights + qws/kws + (xb -> later ctx) region.
  u16* ws  = (u16*)d_ws;
  u16* WqT = ws;                    // [3][1024][1024] stacked (Wq,Wk,Wv)
  u16* WoT = WqT + 3 * NE_W;
  u16* qws = WoT + NE_W;
  u16* kws = qws + NE_X;
  u16* xb  = kws + NE_X;            // lifetime: prep -> QKV
  u16* ctx = xb;                    // lifetime: attn -> final (disjoint)

  // 1. fused prep: casts + all weight packs (9216 blocks)
  prep_fused<<<dim3(9216, 1, 1), 256, 0, stream>>>(x, enc, Wq, Wk, Wv, Wo,
                                                   xb, eb, WqT, WoT);

  // 2. fused QKV projection (8-phase 256x256; 192 blocks, 512 thr)
  gemm_qkv<<<dim3(12, 8, 2), 512, 0, stream>>>(xb, eb, WqT, bq, bk, bv,
                                               qws, kws, vTp);

  // 3. attention (r15: kv-split serial, 512 thr, 2 blocks/CU)
  attn_flash<<<dim3(SQ_ / 128, H_, B_), 512, 0, stream>>>(qws, kws, vTp, ctx);

  // 4. output projection (fp32, overwrites all of d_out; scratch dead)
  gemm_final<<<dim3(8, 32, 2), 256, 0, stream>>>(ctx, WoT, bo, (float*)d_out);
}

// Round 11
// 200.693 us; speedup vs baseline: 1.5857x; 1.0231x over previous
//
#include <hip/hip_runtime.h>

// ---------------------------------------------------------------------------
// CrossMultiHeadedSelfAttention  B=2 SQ=SK=2048 D=1024 H=16 HD=64
// Round 19: attn XCD-chunked block swizzle (T1). Everything else = r18.
//  - attn grid flattened to 512 blocks; orig = (bid&7)*64 + bid>>3 puts 64
//    consecutive logical blocks (= 4 (b,h) pairs = 2 MB KV) on one XCD ->
//    KV fits the 4 MB per-XCD L2 (was: every XCD thrashing the full 16 MB).
//    512 % 8 == 0 -> bijective (m204).
//  - Mechanism target: FETCH_SIZE 70 MB -> ~30 MB; stage-miss latency off
//    the per-tile barrier critical path.
// ---------------------------------------------------------------------------

typedef unsigned short u16;
typedef __bf16 bf16x8 __attribute__((ext_vector_type(8)));
typedef float f32x4 __attribute__((ext_vector_type(4)));
typedef float f32x16 __attribute__((ext_vector_type(16)));
typedef unsigned u32x2 __attribute__((ext_vector_type(2)));

#define B_ 2
#define SQ_ 2048
#define SK_ 2048
#define D_ 1024
#define H_ 16
#define HD_ 64

__device__ __forceinline__ u16 f2bf(float f) {
  union { float f; unsigned u; } c; c.f = f;
  unsigned u = c.u;
  return (u16)((u + 0x7fffu + ((u >> 16) & 1u)) >> 16);  // RNE
}
__device__ __forceinline__ unsigned pack_bf16(float lo, float hi) {
  union { __bf16 h[2]; unsigned u; } c;
  c.h[0] = (__bf16)lo;
  c.h[1] = (__bf16)hi;
  return c.u;
}

#define GLOAD_LDS16(gp, lp)                                                  \
  __builtin_amdgcn_global_load_lds(                                          \
      (const __attribute__((address_space(1))) void*)(gp),                   \
      (__attribute__((address_space(3))) void*)(lp), 16, 0, 0)

// ------------------------------ fused prep ---------------------------------
__global__ __launch_bounds__(256) void prep_fused(const float* __restrict__ x,
                                                  const float* __restrict__ enc,
                                                  const float* __restrict__ Wq,
                                                  const float* __restrict__ Wk,
                                                  const float* __restrict__ Wv,
                                                  const float* __restrict__ Wo,
                                                  u16* __restrict__ xb,
                                                  u16* __restrict__ eb,
                                                  u16* __restrict__ WqT,
                                                  u16* __restrict__ WoT) {
  __shared__ float tile[64][65];
  const int id = blockIdx.x;
  const int tid = threadIdx.x;

  if (id < 8192) {  // ---- casts ----
    const float* in = (id >= 4096) ? enc : x;
    u16* out = (id >= 4096) ? eb : xb;
    int i = (id & 4095) * 256 + tid;
    float4 v = ((const float4*)in)[i];
    uint2 p;
    p.x = (unsigned)f2bf(v.x) | ((unsigned)f2bf(v.y) << 16);
    p.y = (unsigned)f2bf(v.z) | ((unsigned)f2bf(v.w) << 16);
    ((uint2*)out)[i] = p;
    return;
  }

  if (id < 8960) {  // ---- Wq/Wk/Wv transpose: [h][1024][64] -> [n][1024] ----
    const int f = id - 8192;
    const int z48 = f >> 4, y = f & 15;
    const int mat = z48 >> 4, head = z48 & 15;
    const float* W = (mat == 0) ? Wq : (mat == 1 ? Wk : Wv);
    const float* ib = W + (long)head * 65536;                 // [1024][64]
    u16* ob = WqT + ((long)mat << 20) + (long)head * 65536;   // 64 x 1024
    const int r0 = y << 6;
#pragma unroll
    for (int i = 0; i < 16; ++i) {
      int idx = tid + (i << 8);
      int r = idx >> 6, c = idx & 63;
      tile[r][c] = ib[(long)(r0 + r) * 64 + c];
    }
    __syncthreads();
#pragma unroll
    for (int i = 0; i < 16; ++i) {
      int idx = tid + (i << 8);
      int cc = idx >> 6, rr = idx & 63;
      ob[(long)cc * 1024 + (r0 + rr)] = f2bf(tile[rr][cc]);
    }
    return;
  }

  {  // ---- Wo transpose 1024x1024 -> WoT [1024][1024] ----
    const int g = id - 8960;
    const int c0 = (g & 15) << 6, r0 = (g >> 4) << 6;
#pragma unroll
    for (int i = 0; i < 16; ++i) {
      int idx = tid + (i << 8);
      int r = idx >> 6, c = idx & 63;
      tile[r][c] = Wo[(long)(r0 + r) * 1024 + (c0 + c)];
    }
    __syncthreads();
#pragma unroll
    for (int i = 0; i < 16; ++i) {
      int idx = tid + (i << 8);
      int cc = idx >> 6, rr = idx & 63;
      WoT[(long)(c0 + cc) * 1024 + (r0 + rr)] = f2bf(tile[rr][cc]);
    }
  }
}

// ------------------- fused QKV projection (8-phase 256x256) ----------------
// grid (12, 8, 2), 512 thr. seg = N'-range/1024 -> Q/K/V. BK=64, K=1024.
#define QBAR() asm volatile("s_barrier" ::: "memory")
#define VMW4 asm volatile("s_waitcnt vmcnt(4)" ::: "memory")
#define VMW0 asm volatile("s_waitcnt vmcnt(0)" ::: "memory")
#define LGKM0 asm volatile("s_waitcnt lgkmcnt(0)" ::: "memory")
#define PRIO1 __builtin_amdgcn_s_setprio(1)
#define PRIO0 __builtin_amdgcn_s_setprio(0)

// stage one [256][32] kk-slice: 2 glds (rows 0-127, 128-255)
#define ST_SLICE(gp, koff, dstu)                                              \
  do {                                                                        \
    GLOAD_LDS16((gp) + (koff), SMu + (dstu) + tid * 8);                       \
    GLOAD_LDS16((gp) + (koff) + (long)128 * 1024, SMu + (dstu) + 4096 + tid * 8); \
  } while (0)

#define LDA4(dst, bufo, kko, mho)                                             \
  _Pragma("unroll") for (int m2 = 0; m2 < 4; ++m2)                            \
      dst[m2] = *(const bf16x8*)(SMu + (bufo) + (kko) + aob + (mho) + m2 * 512)

#define LDB4(dst, bufo, kko)                                                  \
  _Pragma("unroll") for (int n2 = 0; n2 < 4; ++n2)                            \
      dst[n2] = *(const bf16x8*)(SMu + (bufo) + 16384 + (kko) + bob + n2 * 512)

#define MM16(mh, av, bv_)                                                     \
  _Pragma("unroll") for (int m2 = 0; m2 < 4; ++m2)                            \
  _Pragma("unroll") for (int n2 = 0; n2 < 4; ++n2)                            \
      acc[(mh) * 4 + m2][n2] = __builtin_amdgcn_mfma_f32_16x16x32_bf16(       \
          av[m2], bv_[n2], acc[(mh) * 4 + m2][n2], 0, 0, 0)

// 4 phases of one K-tile. Invariant at tile entry: outstanding = [A1(t),B1(t)],
// and A0(t),B0(t) confirmed (vmcnt4+barrier at end of previous tile).
#define TILE_BODY(bo, so, kn)                                                 \
  {                                                                           \
    bf16x8 aF[4], aG[4], bF[4];                                               \
    /* P0: reads A0,B0(t); stages A0(t+1) */                                  \
    LDA4(aF, bo, 0, 0); LDB4(bF, bo, 0);                                      \
    ST_SLICE(aS, (kn), (so) + 0);                                             \
    QBAR(); LGKM0; PRIO1; MM16(0, aF, bF); PRIO0; QBAR();                     \
    /* P1: reads A0-upper; stages B0(t+1); confirm A1,B1(t) */                \
    LDA4(aG, bo, 0, 2048);                                                    \
    ST_SLICE(bS, (kn), (so) + 16384);                                         \
    QBAR(); LGKM0; PRIO1; MM16(1, aG, bF); PRIO0; VMW4; QBAR();               \
    /* P2: reads A1,B1(t); stages A1(t+1) */                                  \
    LDA4(aF, bo, 8192, 0); LDB4(bF, bo, 8192);                                \
    ST_SLICE(aS, (kn) + 32, (so) + 8192);                                     \
    QBAR(); LGKM0; PRIO1; MM16(0, aF, bF); PRIO0; QBAR();                     \
    /* P3: reads A1-upper; stages B1(t+1); confirm A0,B0(t+1) */              \
    LDA4(aG, bo, 8192, 2048);                                                 \
    ST_SLICE(bS, (kn) + 32, (so) + 24576);                                    \
    QBAR(); LGKM0; PRIO1; MM16(1, aG, bF); PRIO0; VMW4; QBAR();               \
  }

__global__ __launch_bounds__(512) void gemm_qkv(const u16* __restrict__ xb,
                                                const u16* __restrict__ eb,
                                                const u16* __restrict__ Wt3,
                                                const float* __restrict__ bq,
                                                const float* __restrict__ bk,
                                                const float* __restrict__ bv,
                                                u16* __restrict__ qws,
                                                u16* __restrict__ kws,
                                                u16* __restrict__ vT) {
  constexpr int M = 2048, N = 1024, K = 1024;
  // [2 buf][A0 @0, A1 @8192, B0 @16384, B1 @24576] u16. 128 KB total.
  __shared__ __align__(16) u16 SMu[65536];

  const int tid = threadIdx.x;
  const int lane = tid & 63;
  const int wid = tid >> 6;
  const int wm = wid >> 2;          // M half (rows wm*128)
  const int wn = wid & 3;           // N quarter (cols wn*64)
  const int l16 = lane & 15, quad = lane >> 4;
  const int qsw = (quad ^ ((l16 >> 1) & 3)) << 3;   // u16 units
  const int aob = wm * 4096 + l16 * 32 + qsw;
  const int bob = wn * 2048 + l16 * 32 + qsw;

  const int bn0g = blockIdx.x << 8;
  const int seg = bn0g >> 10;       // 0=Q 1=K 2=V (block-uniform)
  const int bn0 = bn0g & (N - 1);
  const int bm0 = blockIdx.y << 8;
  const u16* A = (seg == 0) ? xb : eb;
  const u16* Wt = Wt3 + ((long)seg << 20);
  const float* bias = (seg == 0) ? bq : (seg == 1 ? bk : bv);
  const long abase = (long)blockIdx.z * M * K;

  f32x4 acc[8][4];
#pragma unroll
  for (int i = 0; i < 8; ++i)
#pragma unroll
    for (int j = 0; j < 4; ++j) acc[i][j] = f32x4{0.f, 0.f, 0.f, 0.f};

  // staging: row = tid>>2 (+128 per glds), chunk = tid&3, pre-swizzled source
  const int sr = tid >> 2;
  const int sc2 = ((tid & 3) ^ ((sr >> 1) & 3)) << 3;
  const u16* aS = A + abase + (long)(bm0 + sr) * K + sc2;
  const u16* bS = Wt + (long)(bn0 + sr) * K + sc2;

  // prologue: stage tile 0 (A0,B0,A1,B1); confirm A0,B0 before first reads
  ST_SLICE(aS, 0, 0);
  ST_SLICE(bS, 0, 16384);
  ST_SLICE(aS, 32, 8192);
  ST_SLICE(bS, 32, 24576);
  VMW4; QBAR();

  // tiles 0..13 (pairs), tile 14 stages 15, tile 15 peeled
#pragma unroll 1
  for (int tp = 0; tp < 7; ++tp) {
    const int kb = tp * 128;
    TILE_BODY(0, 32768, kb + 64);
    TILE_BODY(32768, 0, kb + 128);
  }
  TILE_BODY(0, 32768, 960);  // t=14 stages t=15
  {                          // t=15: entering outstanding = [A1(15),B1(15)]
    bf16x8 aF[4], aG[4], bF[4];
    LDA4(aF, 32768, 0, 0); LDB4(bF, 32768, 0);
    QBAR(); LGKM0; PRIO1; MM16(0, aF, bF); PRIO0; QBAR();
    LDA4(aG, 32768, 0, 2048);
    QBAR(); LGKM0; PRIO1; MM16(1, aG, bF); PRIO0; VMW0; QBAR();
    LDA4(aF, 32768, 8192, 0); LDB4(bF, 32768, 8192);
    QBAR(); LGKM0; PRIO1; MM16(0, aF, bF); PRIO0; QBAR();
    LDA4(aG, 32768, 8192, 2048);
    LGKM0; PRIO1; MM16(1, aG, bF); PRIO0;
  }

  float bv4[4];
#pragma unroll
  for (int ni = 0; ni < 4; ++ni) bv4[ni] = bias[bn0 + wn * 64 + ni * 16 + l16];

  if (seg == 2) {  // transposed bf16 out [z][N][M]
    const long zb = (long)blockIdx.z * N * M;
#pragma unroll
    for (int mi = 0; mi < 8; ++mi)
#pragma unroll
      for (int ni = 0; ni < 4; ++ni) {
        int colg = bn0 + wn * 64 + ni * 16 + l16;
        int rowg = bm0 + wm * 128 + mi * 16 + (quad << 2);
        ushort4 pk = make_ushort4(f2bf(acc[mi][ni][0] + bv4[ni]),
                                  f2bf(acc[mi][ni][1] + bv4[ni]),
                                  f2bf(acc[mi][ni][2] + bv4[ni]),
                                  f2bf(acc[mi][ni][3] + bv4[ni]));
        *(ushort4*)(vT + zb + (long)colg * M + rowg) = pk;
      }
  } else {
    u16* outp = seg ? kws : qws;
    const long cbase = (long)blockIdx.z * M * N;
#pragma unroll
    for (int mi = 0; mi < 8; ++mi)
#pragma unroll
      for (int ni = 0; ni < 4; ++ni)
#pragma unroll
        for (int r = 0; r < 4; ++r) {
          int row = bm0 + wm * 128 + mi * 16 + (quad << 2) + r;
          int col = bn0 + wn * 64 + ni * 16 + l16;
          outp[cbase + (long)row * N + col] = f2bf(acc[mi][ni][r] + bv4[ni]);
        }
  }
}

// ------------------------- final GEMM (64x128 tile, BK=64) -----------------
__global__ __launch_bounds__(256) void gemm_final(const u16* __restrict__ A,
                                                  const u16* __restrict__ Wt,
                                                  const float* __restrict__ bias,
                                                  float* __restrict__ C) {
  constexpr int M = 2048, N = 1024, K = 1024;
  __shared__ __align__(16) u16 As[64 * 64];    // 8 KB
  __shared__ __align__(16) u16 Bs[128 * 64];   // 16 KB
  const int tid = threadIdx.x;
  const int lane = tid & 63;
  const int wid = tid >> 6;
  const int l16 = lane & 15, quad = lane >> 4;
  const int bn0 = blockIdx.x << 7, bm0 = blockIdx.y << 6;

  f32x4 acc[4][2];
#pragma unroll
  for (int i = 0; i < 4; ++i)
#pragma unroll
    for (int j = 0; j < 2; ++j) acc[i][j] = f32x4{0.f, 0.f, 0.f, 0.f};

  const int r0 = tid >> 3;
  const int c0s = ((tid & 7) ^ (r0 & 7)) << 3;
  const long abase = (long)blockIdx.z * M * K;
  const u16* agp = A + abase + (long)(bm0 + r0) * K + c0s;
  const u16* bgp = Wt + (long)(bn0 + r0) * K + c0s;
  u16* alp = As + tid * 8;
  u16* blp = Bs + tid * 8;

  for (int k0 = 0; k0 < K; k0 += 64) {
#pragma unroll
    for (int i = 0; i < 2; ++i)
      GLOAD_LDS16(agp + k0 + (long)(32 * i) * K, alp + i * 2048);
#pragma unroll
    for (int i = 0; i < 4; ++i)
      GLOAD_LDS16(bgp + k0 + (long)(32 * i) * K, blp + i * 2048);
    __syncthreads();
#pragma unroll
    for (int kk = 0; kk < 2; ++kk) {
      const int csw = ((quad + 4 * kk) ^ (l16 & 7)) << 3;
      bf16x8 af[4], bfr[2];
#pragma unroll
      for (int mi = 0; mi < 4; ++mi)
        af[mi] = *(const bf16x8*)(As + (mi * 16 + l16) * 64 + csw);
#pragma unroll
      for (int ni = 0; ni < 2; ++ni)
        bfr[ni] = *(const bf16x8*)(Bs + (wid * 32 + ni * 16 + l16) * 64 + csw);
#pragma unroll
      for (int mi = 0; mi < 4; ++mi)
#pragma unroll
        for (int ni = 0; ni < 2; ++ni)
          acc[mi][ni] = __builtin_amdgcn_mfma_f32_16x16x32_bf16(af[mi], bfr[ni],
                                                                acc[mi][ni], 0, 0, 0);
    }
    __syncthreads();
  }

  float bv2[2];
#pragma unroll
  for (int ni = 0; ni < 2; ++ni) bv2[ni] = bias[bn0 + wid * 32 + ni * 16 + l16];
  const long cbase = (long)blockIdx.z * M * N;
#pragma unroll
  for (int mi = 0; mi < 4; ++mi)
#pragma unroll
    for (int ni = 0; ni < 2; ++ni)
#pragma unroll
      for (int r = 0; r < 4; ++r) {
        int row = bm0 + mi * 16 + (quad << 2) + r;
        int col = bn0 + wid * 32 + ni * 16 + l16;
        C[cbase + (long)row * N + col] = acc[mi][ni][r] + bv2[ni];
      }
}

// --------------------------- flash attention (r19) -------------------------
// r15 loop + XCD-chunked block swizzle: 1D grid of 512 blocks;
// orig = (bid&7)*64 + bid>>3 -> each XCD owns 4 (b,h) pairs (2 MB KV in L2).
#define ATTN_STAGE(kbase, vbase)                                              \
  do {                                                                        \
    GLOAD_LDS16(kp, (kbase) + st * 8);                                        \
    GLOAD_LDS16(kp + (long)32 * D_, (kbase) + 2048 + st * 8);                 \
    GLOAD_LDS16(vp, (vbase) + st * 8);                                        \
    GLOAD_LDS16(vp + (long)32 * SK_, (vbase) + 2048 + st * 8);                \
    kp += (long)64 * D_;                                                      \
    vp += 64;                                                                 \
  } while (0)

#define QK_BLOCK(Kb, sx0, sx1)                                                \
  do {                                                                        \
    {                                                                         \
      bf16x8 kf0 = *(const bf16x8*)((Kb) + ro0 + sw[0]);                      \
      bf16x8 kf1 = *(const bf16x8*)((Kb) + 2048 + ro0 + sw[0]);               \
      sx0 = __builtin_amdgcn_mfma_f32_32x32x16_bf16(kf0, qf[0], ZV, 0, 0, 0); \
      sx1 = __builtin_amdgcn_mfma_f32_32x32x16_bf16(kf1, qf[0], ZV, 0, 0, 0); \
    }                                                                         \
    _Pragma("unroll") for (int j = 1; j < 4; ++j) {                           \
      bf16x8 kf0 = *(const bf16x8*)((Kb) + ro0 + sw[j]);                      \
      bf16x8 kf1 = *(const bf16x8*)((Kb) + 2048 + ro0 + sw[j]);               \
      sx0 = __builtin_amdgcn_mfma_f32_32x32x16_bf16(kf0, qf[j], sx0, 0, 0, 0);\
      sx1 = __builtin_amdgcn_mfma_f32_32x32x16_bf16(kf1, qf[j], sx1, 0, 0, 0);\
    }                                                                         \
  } while (0)

#define EXPD(sx0, sx1)                                                        \
  do {                                                                        \
    _Pragma("unroll") for (int g = 0; g < 8; ++g) {                           \
      float a0 = __expf(sx0[2 * g]);                                          \
      float a1 = __expf(sx0[2 * g + 1]);                                      \
      float b0 = __expf(sx1[2 * g]);                                          \
      float b1 = __expf(sx1[2 * g + 1]);                                      \
      psA += a0 + a1;                                                         \
      psB += b0 + b1;                                                         \
      d0[g] = pack_bf16(a0, a1);                                              \
      d1[g] = pack_bf16(b0, b1);                                              \
    }                                                                         \
  } while (0)

#define PV_KS(Vb, dd, k1, ks)                                                 \
  do {                                                                        \
    u32x2 sA = __builtin_amdgcn_permlane32_swap(dd[4 * (k1)],                 \
                                                dd[4 * (k1) + 2], false,      \
                                                false);                       \
    u32x2 sB = __builtin_amdgcn_permlane32_swap(dd[4 * (k1) + 1],             \
                                                dd[4 * (k1) + 3], false,      \
                                                false);                       \
    union { unsigned u[4]; bf16x8 v; } pa;                                    \
    pa.u[0] = sA[0]; pa.u[1] = sB[0]; pa.u[2] = sA[1]; pa.u[3] = sB[1];       \
    bf16x8 v0 = *(const bf16x8*)((Vb) + ro0 + sw[ks]);                        \
    bf16x8 v1 = *(const bf16x8*)((Vb) + 2048 + ro0 + sw[ks]);                 \
    o0 = __builtin_amdgcn_mfma_f32_32x32x16_bf16(pa.v, v0, o0, 0, 0, 0);      \
    o1 = __builtin_amdgcn_mfma_f32_32x32x16_bf16(pa.v, v1, o1, 0, 0, 0);      \
  } while (0)

#define PV4(Vb)                                                               \
  do {                                                                        \
    PV_KS(Vb, d0, 0, 0);                                                      \
    PV_KS(Vb, d0, 1, 1);                                                      \
    PV_KS(Vb, d1, 0, 2);                                                      \
    PV_KS(Vb, d1, 1, 3);                                                      \
  } while (0)

__global__ __launch_bounds__(512) void attn_flash(const u16* __restrict__ q,
                                                  const u16* __restrict__ k,
                                                  const u16* __restrict__ vT,
                                                  u16* __restrict__ ctx) {
  __shared__ __align__(16) u16 SM[32768];  // 64 KB

  const int tid = threadIdx.x;
  const int lane = tid & 63;
  const int wid = tid >> 6;
  const int half = wid >> 2;
  const int wq = wid & 3;
  const int l31 = lane & 31, h5 = lane >> 5;

  // XCD-chunked swizzle: launch-bid -> logical block (bijective, 512%8==0)
  const int bid0 = blockIdx.x;
  const int orig = ((bid0 & 7) << 6) + (bid0 >> 3);
  const int qx = orig & 15;
  const int h = (orig >> 4) & 15;
  const int b = orig >> 8;
  const int q0w = (qx << 7) + (wq << 5);

  u16* Ksh = SM + half * 8192;
  u16* Vsh = SM + 16384 + half * 8192;

  bf16x8 qf[4];
  const u16* qp = q + ((long)(b * SQ_ + q0w + l31) * D_ + h * HD_ + 8 * h5);
#pragma unroll
  for (int j = 0; j < 4; ++j) {
    bf16x8 t = *(const bf16x8*)(qp + 16 * j);
#pragma unroll
    for (int e = 0; e < 8; ++e) t[e] = (__bf16)((float)t[e] * 0.125f);
    qf[j] = t;
  }

  const int st = tid & 255;
  const int srow = st >> 3;
  const int ssw = ((st & 7) ^ (srow & 7)) << 3;
  const u16* kp = k + ((long)(b * SK_ + (half << 10) + srow) * D_ + h * HD_ + ssw);
  const u16* vp = vT + ((long)(b * D_ + h * HD_ + srow) * SK_ + (half << 10) + ssw);

  const int ro0 = l31 << 6;
  int sw[4];
#pragma unroll
  for (int i = 0; i < 4; ++i) sw[i] = ((2 * i + h5) ^ (lane & 7)) << 3;

  f32x16 o0, o1, sA0, sA1;
  f32x16 ZV = {};
#pragma unroll
  for (int i = 0; i < 16; ++i) { o0[i] = 0.f; o1[i] = 0.f; }
  float psA = 0.f, psB = 0.f;
  unsigned d0[8], d1[8];

  ATTN_STAGE(Ksh, Vsh);  // tile 0 of this half -> buf 0

  for (int t = 0; t < 16; ++t) {
    const int cur = t & 1;
    __syncthreads();
    if (t < 15) ATTN_STAGE(Ksh + (cur ^ 1) * 4096, Vsh + (cur ^ 1) * 4096);
    QK_BLOCK(Ksh + cur * 4096, sA0, sA1);
    EXPD(sA0, sA1);
    PV4(Vsh + cur * 4096);
  }

  float ps = psA + psB;
  ps += __shfl_xor(ps, 32, 64);

  __syncthreads();
  float* cb = (float*)SM;
  const int wl = (wq << 6) | lane;
  if (half) {
#pragma unroll
    for (int r = 0; r < 16; ++r) {
      cb[r * 257 + wl] = o0[r];
      cb[(r + 16) * 257 + wl] = o1[r];
    }
    cb[8300 + wl] = ps;
  }
  __syncthreads();
  if (!half) {
#pragma unroll
    for (int r = 0; r < 16; ++r) {
      o0[r] += cb[r * 257 + wl];
      o1[r] += cb[(r + 16) * 257 + wl];
    }
    ps += cb[8300 + wl];
    float inv = 1.f / ps;
#pragma unroll
    for (int r = 0; r < 16; ++r) {
      const int crow = (r & 3) + 8 * (r >> 2) + 4 * h5;
      float dq = __shfl(inv, crow, 64);
      long base = (long)(b * SQ_ + q0w + crow) * D_ + h * HD_ + l31;
      ctx[base] = f2bf(o0[r] * dq);
      ctx[base + 32] = f2bf(o1[r] * dq);
    }
  }
}

// ---------------------------------------------------------------------------
extern "C" void kernel_launch(void* const* d_in, const int* in_sizes, int n_in,
                              void* d_out, int out_size, void* d_ws, size_t ws_size,
                              hipStream_t stream) {
  const float* x   = (const float*)d_in[0];
  const float* enc = (const float*)d_in[1];
  const float* Wq  = (const float*)d_in[2];
  const float* bq  = (const float*)d_in[3];
  const float* Wk  = (const float*)d_in[4];
  const float* bk  = (const float*)d_in[5];
  const float* Wv  = (const float*)d_in[6];
  const float* bv  = (const float*)d_in[7];
  const float* Wo  = (const float*)d_in[8];
  const float* bo  = (const float*)d_in[9];

  const long NE_X = (long)B_ * SQ_ * D_;  // 4,194,304
  const long NE_W = (long)D_ * D_;        // 1,048,576

  // d_out (16 MiB) scratch: outA = vTp, outB = eb.
  u16* outA = (u16*)d_out;
  u16* outB = outA + NE_X;
  u16* eb  = outB;
  u16* vTp = outA;

  // d_ws (32 MiB): weights + qws/kws + (xb -> later ctx) region.
  u16* ws  = (u16*)d_ws;
  u16* WqT = ws;                    // [3][1024][1024] stacked (Wq,Wk,Wv)
  u16* WoT = WqT + 3 * NE_W;
  u16* qws = WoT + NE_W;
  u16* kws = qws + NE_X;
  u16* xb  = kws + NE_X;            // lifetime: prep -> QKV
  u16* ctx = xb;                    // lifetime: attn -> final (disjoint)

  // 1. fused prep: casts + all weight packs (9216 blocks)
  prep_fused<<<dim3(9216, 1, 1), 256, 0, stream>>>(x, enc, Wq, Wk, Wv, Wo,
                                                   xb, eb, WqT, WoT);

  // 2. fused QKV projection (8-phase 256x256; 192 blocks, 512 thr)
  gemm_qkv<<<dim3(12, 8, 2), 512, 0, stream>>>(xb, eb, WqT, bq, bk, bv,
                                               qws, kws, vTp);

  // 3. attention (r15 loop + XCD-chunked swizzle; 512 blocks 1-D)
  attn_flash<<<dim3(512, 1, 1), 512, 0, stream>>>(qws, kws, vTp, ctx);

  // 4. output projection (fp32, overwrites all of d_out; scratch dead)
  gemm_final<<<dim3(8, 32, 2), 256, 0, stream>>>(ctx, WoT, bo, (float*)d_out);
}